// Round 11
// baseline (1732.011 us; speedup 1.0000x reference)
//
#include <hip/hip_runtime.h>
#include <math.h>

constexpr int B = 8;
constexpr int N = 50000;
constexpr int E = 400000;
constexpr int NH = 25000;
constexpr float BN_EPS = 1e-5f;
constexpr float NEG = 0.01f;

// ------------------------- bf16 helpers -------------------------

__device__ __forceinline__ unsigned clamp_src(int s) {
    unsigned u = (unsigned)s;
    return (u < (unsigned)N) ? u : 0u;
}

__device__ __forceinline__ unsigned pack_bf16(float a, float b) {
    unsigned ua = __float_as_uint(a);
    unsigned ub = __float_as_uint(b);
    ua = (ua + 0x7FFFu + ((ua >> 16) & 1u)) >> 16;
    ub = (ub + 0x7FFFu + ((ub >> 16) & 1u)) >> 16;
    return (ub << 16) | (ua & 0xFFFFu);
}
__device__ __forceinline__ float unpack_lo(unsigned u) { return __uint_as_float(u << 16); }
__device__ __forceinline__ float unpack_hi(unsigned u) { return __uint_as_float(u & 0xFFFF0000u); }

// ------------------------- CSR construction (source-bucketed) -------------------------

__global__ __launch_bounds__(256) void deg2_kernel(const int* __restrict__ row, const int* __restrict__ col,
                                                   float* __restrict__ deg, int* __restrict__ deg_lo) {
    int e = blockIdx.x * blockDim.x + threadIdx.x;
    if (e >= E) return;
    unsigned r = clamp_src(row[e]), c = clamp_src(col[e]);
    atomicAdd(&deg[c], 1.0f);
    if (r < (unsigned)NH) atomicAdd(&deg_lo[c], 1);
}

__global__ __launch_bounds__(256) void scan1_kernel(const float* __restrict__ deg,
                                                    int* __restrict__ part, int* __restrict__ bsum) {
    __shared__ int sm[4];
    int i = blockIdx.x * blockDim.x + threadIdx.x;
    int v = (i < N) ? (int)deg[i] : 0;
    int lane = threadIdx.x & 63, wv = threadIdx.x >> 6;
    int x = v;
#pragma unroll
    for (int off = 1; off < 64; off <<= 1) {
        int t = __shfl_up(x, off);
        if (lane >= off) x += t;
    }
    if (lane == 63) sm[wv] = x;
    __syncthreads();
    int add = 0;
#pragma unroll
    for (int w = 0; w < 4; ++w) if (w < wv) add += sm[w];
    if (i < N) part[i] = x - v + add;
    if (threadIdx.x == blockDim.x - 1) bsum[blockIdx.x] = x + add;
}

__global__ __launch_bounds__(256) void scan2_kernel(const int* __restrict__ bsum, int* __restrict__ boff,
                                                    int nb, int* __restrict__ rowptr) {
    __shared__ int sm[4];
    int i = threadIdx.x;
    int v = (i < nb) ? bsum[i] : 0;
    int lane = i & 63, wv = i >> 6;
    int x = v;
#pragma unroll
    for (int off = 1; off < 64; off <<= 1) {
        int t = __shfl_up(x, off);
        if (lane >= off) x += t;
    }
    if (lane == 63) sm[wv] = x;
    __syncthreads();
    int add = 0;
#pragma unroll
    for (int w = 0; w < 4; ++w) if (w < wv) add += sm[w];
    if (i < nb) boff[i] = x - v + add;
    if (i == 0) rowptr[N] = E;
}

// scan3 + dis fused: rowptr finalize and deg -> deg^-1/2 in place
__global__ __launch_bounds__(256) void scan3_dis_kernel(const int* __restrict__ part, const int* __restrict__ boff,
                                                        int* __restrict__ rowptr, float* __restrict__ deg) {
    int i = blockIdx.x * blockDim.x + threadIdx.x;
    if (i < N) {
        rowptr[i] = part[i] + boff[blockIdx.x];
        float d = deg[i];
        deg[i] = (d > 0.f) ? rsqrtf(d) : 0.f;
    }
}

__global__ __launch_bounds__(256) void fill_kernel(const int* __restrict__ row, const int* __restrict__ col,
                                                   const int* __restrict__ rowptr, const int* __restrict__ deg_lo,
                                                   int* __restrict__ cur_lo, int* __restrict__ cur_hi,
                                                   int* __restrict__ csr_src) {
    int e = blockIdx.x * blockDim.x + threadIdx.x;
    if (e >= E) return;
    unsigned r = clamp_src(row[e]), c = clamp_src(col[e]);
    unsigned p;
    if (r < (unsigned)NH)
        p = (unsigned)(rowptr[c] + atomicAdd(&cur_lo[c], 1));
    else
        p = (unsigned)(rowptr[c] + deg_lo[c] + atomicAdd(&cur_hi[c], 1));
    if (p >= (unsigned)E) p = E - 1;
    csr_src[p] = (int)r;
}

// ------------------------- 4-dim propagation (layer 0), batch-pinned, bf16 out ---------

template<bool INBF>
__global__ __launch_bounds__(256) void xprop_kernel(const void* __restrict__ xin, const int* __restrict__ rowptr,
                                                    const int* __restrict__ csr_src, const float* __restrict__ dis,
                                                    uint2* __restrict__ xout) {
    int b = blockIdx.x & 7;
    int n = (blockIdx.x >> 3) * blockDim.x + threadIdx.x;
    if (n >= N) return;
    float a0 = 0.f, a1 = 0.f, a2 = 0.f, a3 = 0.f;
    int beg = rowptr[n], end = rowptr[n + 1];
    if (beg < 0) beg = 0;
    if (end > E) end = E;
    for (int i = beg; i < end; ++i) {
        unsigned s = clamp_src(csr_src[i]);
        float w = dis[s];
        if constexpr (!INBF) {
            float4 v = *((const float4*)xin + (size_t)b * N + s);
            a0 = fmaf(w, v.x, a0); a1 = fmaf(w, v.y, a1);
            a2 = fmaf(w, v.z, a2); a3 = fmaf(w, v.w, a3);
        } else {
            uint2 v = *((const uint2*)xin + (size_t)b * N + s);
            a0 = fmaf(w, unpack_lo(v.x), a0); a1 = fmaf(w, unpack_hi(v.x), a1);
            a2 = fmaf(w, unpack_lo(v.y), a2); a3 = fmaf(w, unpack_hi(v.y), a3);
        }
    }
    float dn = dis[n];
    uint2 o;
    o.x = pack_bf16(a0 * dn, a1 * dn);
    o.y = pack_bf16(a2 * dn, a3 * dn);
    xout[(size_t)b * N + n] = o;
}

// ------------------------- 16-dim concat row loader -------------------------

__device__ __forceinline__ void load_xv(const float4* __restrict__ x0, const uint2* __restrict__ x1,
                                        const uint2* __restrict__ x2, const uint2* __restrict__ x3,
                                        size_t ro, float xv[16]) {
    float4 v = x0[ro];
    xv[0] = v.x; xv[1] = v.y; xv[2] = v.z; xv[3] = v.w;
    uint2 u1 = x1[ro], u2 = x2[ro], u3 = x3[ro];
    xv[4] = unpack_lo(u1.x); xv[5] = unpack_hi(u1.x); xv[6] = unpack_lo(u1.y); xv[7] = unpack_hi(u1.y);
    xv[8] = unpack_lo(u2.x); xv[9] = unpack_hi(u2.x); xv[10] = unpack_lo(u2.y); xv[11] = unpack_hi(u2.y);
    xv[12] = unpack_lo(u3.x); xv[13] = unpack_hi(u3.x); xv[14] = unpack_lo(u3.y); xv[15] = unpack_hi(u3.y);
}

// ------------------------- build h1: ILP-restructured BN shuffles -------------------------

__global__ __launch_bounds__(256) void build_h1_kernel(const float4* __restrict__ x0, const uint2* __restrict__ x1,
                                                       const uint2* __restrict__ x2, const uint2* __restrict__ x3,
                                                       const float* __restrict__ W0,
                                                       const float* __restrict__ gamma, const float* __restrict__ beta,
                                                       uint4* __restrict__ h1) {
    int gid = blockIdx.x * blockDim.x + threadIdx.x;
    int node = gid >> 6;
    int lane = gid & 63;
    int fg = lane >> 3, b = lane & 7;
    if (node >= N) return;
    size_t ro = (size_t)b * N + node;
    float xv[16];
    load_xv(x0, x1, x2, x3, ro, xv);
    float z[8];
#pragma unroll
    for (int j = 0; j < 8; ++j) z[j] = 0.f;
#pragma unroll
    for (int kf = 0; kf < 16; ++kf) {
        const float* wr = W0 + kf * 64 + fg * 8;
        float4 wa = *(const float4*)wr;
        float4 wb = *(const float4*)(wr + 4);
        float xs = xv[kf];
        z[0] = fmaf(xs, wa.x, z[0]); z[1] = fmaf(xs, wa.y, z[1]);
        z[2] = fmaf(xs, wa.z, z[2]); z[3] = fmaf(xs, wa.w, z[3]);
        z[4] = fmaf(xs, wb.x, z[4]); z[5] = fmaf(xs, wb.y, z[5]);
        z[6] = fmaf(xs, wb.z, z[6]); z[7] = fmaf(xs, wb.w, z[7]);
    }
    // BN over batch: 16 independent butterfly chains in 3 rounds (latency-hiding)
    float s[8], s2[8];
#pragma unroll
    for (int j = 0; j < 8; ++j) { s[j] = z[j]; s2[j] = z[j] * z[j]; }
#pragma unroll
    for (int off = 1; off < 8; off <<= 1) {
#pragma unroll
        for (int j = 0; j < 8; ++j) {
            s[j] += __shfl_xor(s[j], off);
            s2[j] += __shfl_xor(s2[j], off);
        }
    }
    const float* gp = gamma + (size_t)node * 64 + fg * 8;
    const float* bp = beta + (size_t)node * 64 + fg * 8;
    float h[8];
#pragma unroll
    for (int j = 0; j < 8; ++j) {
        float mean = s[j] * 0.125f;
        float var = fmaf(-mean, mean, s2[j] * 0.125f);
        float rs = rsqrtf(var + BN_EPS);
        float o = fmaf(gp[j] * rs, z[j] - mean, bp[j]);
        h[j] = (o >= 0.f) ? o : NEG * o;
    }
    uint4 o;
    o.x = pack_bf16(h[0], h[1]);
    o.y = pack_bf16(h[2], h[3]);
    o.z = pack_bf16(h[4], h[5]);
    o.w = pack_bf16(h[6], h[7]);
    h1[ro * 8 + fg] = o;
}

// ------------------------- hopG: feature-half wave-split Horner hop -------------------------
// Block = 128 nodes x 2 feature-halves, 4 waves: w = tid>>6; sub = w&1 (node subgroup),
// half = w>>1 (feature half, WAVE-UNIFORM -> W stays SGPR-broadcast).
// Lane owns node n = g*128 + sub*64 + lane. Gather loads only its 64B half-row (4xdwordx4
// per edge, full per-lane MLP). acc[32]. Dense: full h row read, W column-slice via s_load.
// Store: pack to padded LDS (stride 33), __syncthreads, flat remap -> 64B-contiguous stores
// per thread (no partial-line RMW).
// MODE 0: u_out = h1@Wk. MODE 1: u_out = dis_n*(A' u_in) + h1@Wk. MODE 2: + bias.

template<int MODE>
__global__ __launch_bounds__(256, 6) void hopG_kernel(const unsigned* __restrict__ u_in, const int* __restrict__ rowptr,
                                                      const int* __restrict__ csr_src, const float* __restrict__ dis,
                                                      const uint4* __restrict__ h1, int b0, int bmask, int bshift,
                                                      const float* __restrict__ Wk, const float* __restrict__ bias,
                                                      uint4* __restrict__ u_out) {
    __shared__ unsigned lds[128 * 33];
    int bl = blockIdx.x & bmask;
    int g  = blockIdx.x >> bshift;
    int tid = threadIdx.x;
    int w = tid >> 6, lane = tid & 63;
    int sub = w & 1, half = w >> 1;
    int n = g * 128 + sub * 64 + lane;
    int nc = (n < N) ? n : N - 1;

    float acc[32];
#pragma unroll
    for (int c = 0; c < 32; ++c) acc[c] = 0.f;

    if constexpr (MODE > 0) {
        const uint4* U4 = (const uint4*)u_in;
        int beg = rowptr[nc], end = rowptr[nc + 1];
        if (beg < 0) beg = 0;
        if (end > E) end = E;
        if (n >= N) end = beg;
        for (int i = beg; i < end; ++i) {
            unsigned s = clamp_src(csr_src[i]);
            float wgt = dis[s];
            const uint4* ur = U4 + ((size_t)bl * N + s) * 8 + half * 4;
            uint4 r0 = ur[0], r1 = ur[1], r2 = ur[2], r3 = ur[3];
            acc[0]  = fmaf(wgt, unpack_lo(r0.x), acc[0]);  acc[1]  = fmaf(wgt, unpack_hi(r0.x), acc[1]);
            acc[2]  = fmaf(wgt, unpack_lo(r0.y), acc[2]);  acc[3]  = fmaf(wgt, unpack_hi(r0.y), acc[3]);
            acc[4]  = fmaf(wgt, unpack_lo(r0.z), acc[4]);  acc[5]  = fmaf(wgt, unpack_hi(r0.z), acc[5]);
            acc[6]  = fmaf(wgt, unpack_lo(r0.w), acc[6]);  acc[7]  = fmaf(wgt, unpack_hi(r0.w), acc[7]);
            acc[8]  = fmaf(wgt, unpack_lo(r1.x), acc[8]);  acc[9]  = fmaf(wgt, unpack_hi(r1.x), acc[9]);
            acc[10] = fmaf(wgt, unpack_lo(r1.y), acc[10]); acc[11] = fmaf(wgt, unpack_hi(r1.y), acc[11]);
            acc[12] = fmaf(wgt, unpack_lo(r1.z), acc[12]); acc[13] = fmaf(wgt, unpack_hi(r1.z), acc[13]);
            acc[14] = fmaf(wgt, unpack_lo(r1.w), acc[14]); acc[15] = fmaf(wgt, unpack_hi(r1.w), acc[15]);
            acc[16] = fmaf(wgt, unpack_lo(r2.x), acc[16]); acc[17] = fmaf(wgt, unpack_hi(r2.x), acc[17]);
            acc[18] = fmaf(wgt, unpack_lo(r2.y), acc[18]); acc[19] = fmaf(wgt, unpack_hi(r2.y), acc[19]);
            acc[20] = fmaf(wgt, unpack_lo(r2.z), acc[20]); acc[21] = fmaf(wgt, unpack_hi(r2.z), acc[21]);
            acc[22] = fmaf(wgt, unpack_lo(r2.w), acc[22]); acc[23] = fmaf(wgt, unpack_hi(r2.w), acc[23]);
            acc[24] = fmaf(wgt, unpack_lo(r3.x), acc[24]); acc[25] = fmaf(wgt, unpack_hi(r3.x), acc[25]);
            acc[26] = fmaf(wgt, unpack_lo(r3.y), acc[26]); acc[27] = fmaf(wgt, unpack_hi(r3.y), acc[27]);
            acc[28] = fmaf(wgt, unpack_lo(r3.z), acc[28]); acc[29] = fmaf(wgt, unpack_hi(r3.z), acc[29]);
            acc[30] = fmaf(wgt, unpack_lo(r3.w), acc[30]); acc[31] = fmaf(wgt, unpack_hi(r3.w), acc[31]);
        }
        float dn = dis[nc];
#pragma unroll
        for (int c = 0; c < 32; ++c) acc[c] *= dn;
    }
    if constexpr (MODE == 2) {
        const float* bp = bias + half * 32;
#pragma unroll
        for (int c = 0; c < 32; ++c) acc[c] += bp[c];
    }

    // dense: full h row (8 uint4), W column-slice wave-uniform
    {
        const uint4* hr = h1 + ((size_t)(b0 + bl) * N + nc) * 8;
#pragma unroll 2
        for (int kk = 0; kk < 8; ++kk) {
            uint4 hv = hr[kk];
            unsigned hs[4] = {hv.x, hv.y, hv.z, hv.w};
#pragma unroll
            for (int t = 0; t < 4; ++t) {
                int k = kk * 8 + t * 2;
                float h0 = unpack_lo(hs[t]);
                float h1f = unpack_hi(hs[t]);
                const float* w0 = Wk + k * 64 + half * 32;
                const float* w1 = w0 + 64;
#pragma unroll
                for (int c = 0; c < 32; ++c) acc[c] = fmaf(h0, w0[c], acc[c]);
#pragma unroll
                for (int c = 0; c < 32; ++c) acc[c] = fmaf(h1f, w1[c], acc[c]);
            }
        }
    }

    // pack -> LDS (stride 33: conflict-free u32 writes)
    {
        unsigned* Lr = lds + (sub * 64 + lane) * 33 + half * 16;
#pragma unroll
        for (int q = 0; q < 16; ++q)
            Lr[q] = pack_bf16(acc[2 * q], acc[2 * q + 1]);
    }
    __syncthreads();

    // flat remapped store: thread t -> uint4 flat indices [4t, 4t+4) of block's 128x8-uint4 region
    {
        int f = tid * 4;
        int row = f >> 3;                 // 0..127, each thread within one row
        int nout = g * 128 + row;
        if (nout < N) {
            const unsigned* Ls = lds + row * 33 + (f & 7) * 4;
            uint4* op = u_out + ((size_t)bl * N + (size_t)g * 128) * 8 + f;
#pragma unroll
            for (int j = 0; j < 4; ++j) {
                uint4 v;
                v.x = Ls[j * 4 + 0]; v.y = Ls[j * 4 + 1];
                v.z = Ls[j * 4 + 2]; v.w = Ls[j * 4 + 3];
                op[j] = v;
            }
        }
    }
}

// ------------------------- BN1 + leaky + W2 projection (ILP rounds) -------------------------

__global__ __launch_bounds__(256) void bn_project_kernel(const uint4* __restrict__ zlo, const uint4* __restrict__ zhi,
                                                         const float* __restrict__ gamma, const float* __restrict__ beta,
                                                         const float* __restrict__ W2, float* __restrict__ y) {
    int gid = blockIdx.x * blockDim.x + threadIdx.x;
    int node = gid >> 6;
    int lane = gid & 63;
    int fg = lane >> 3, b = lane & 7;
    if (node >= N) return;
    const uint4* zp = (b < 4) ? (zlo + ((size_t)b * N + node) * 8)
                              : (zhi + ((size_t)(b - 4) * N + node) * 8);
    uint4 v = zp[fg];
    float h[8] = {unpack_lo(v.x), unpack_hi(v.x), unpack_lo(v.y), unpack_hi(v.y),
                  unpack_lo(v.z), unpack_hi(v.z), unpack_lo(v.w), unpack_hi(v.w)};
    float s[8], s2[8];
#pragma unroll
    for (int j = 0; j < 8; ++j) { s[j] = h[j]; s2[j] = h[j] * h[j]; }
#pragma unroll
    for (int off = 1; off < 8; off <<= 1) {
#pragma unroll
        for (int j = 0; j < 8; ++j) {
            s[j] += __shfl_xor(s[j], off);
            s2[j] += __shfl_xor(s2[j], off);
        }
    }
    const float* gp = gamma + (size_t)node * 64 + fg * 8;
    const float* bp = beta + (size_t)node * 64 + fg * 8;
#pragma unroll
    for (int j = 0; j < 8; ++j) {
        float mean = s[j] * 0.125f;
        float var = fmaf(-mean, mean, s2[j] * 0.125f);
        float rs = rsqrtf(var + BN_EPS);
        float o = fmaf(gp[j] * rs, h[j] - mean, bp[j]);
        h[j] = (o >= 0.f) ? o : NEG * o;
    }
    float p[12];
#pragma unroll
    for (int k = 0; k < 4; ++k) {
#pragma unroll
        for (int c = 0; c < 3; ++c) {
            float sv = 0.f;
#pragma unroll
            for (int j = 0; j < 8; ++j)
                sv = fmaf(h[j], W2[k * 192 + (fg * 8 + j) * 3 + c], sv);
            p[k * 3 + c] = sv;
        }
    }
#pragma unroll
    for (int t = 8; t < 64; t <<= 1) {
#pragma unroll
        for (int i = 0; i < 12; ++i)
            p[i] += __shfl_xor(p[i], t);
    }
    if (fg == 0) {
        size_t bn3 = ((size_t)b * N + node) * 3;
#pragma unroll
        for (int k = 0; k < 4; ++k)
#pragma unroll
            for (int c = 0; c < 3; ++c)
                y[(size_t)k * B * N * 3 + bn3 + c] = p[k * 3 + c];
    }
}

// ------------------------- 3-dim propagation (layer 2 Horner) -------------------------

__global__ __launch_bounds__(256) void qprop_kernel(const float* __restrict__ vin, const int* __restrict__ rowptr,
                                                    const int* __restrict__ csr_src, const float* __restrict__ dis,
                                                    const float* __restrict__ add, float* __restrict__ vout) {
    int b = blockIdx.x & 7;
    int n = (blockIdx.x >> 3) * blockDim.x + threadIdx.x;
    if (n >= N) return;
    float a0 = 0.f, a1 = 0.f, a2 = 0.f;
    int beg = rowptr[n], end = rowptr[n + 1];
    if (beg < 0) beg = 0;
    if (end > E) end = E;
    const float* base = vin + (size_t)b * N * 3;
    for (int i = beg; i < end; ++i) {
        unsigned s = clamp_src(csr_src[i]);
        float w = dis[s];
        const float* p = base + (size_t)s * 3;
        a0 = fmaf(w, p[0], a0);
        a1 = fmaf(w, p[1], a1);
        a2 = fmaf(w, p[2], a2);
    }
    float dn = dis[n];
    const float* ap = add + ((size_t)b * N + n) * 3;
    float* op = vout + ((size_t)b * N + n) * 3;
    op[0] = fmaf(a0, dn, ap[0]);
    op[1] = fmaf(a1, dn, ap[1]);
    op[2] = fmaf(a2, dn, ap[2]);
}

__global__ __launch_bounds__(256) void qfinal_kernel(const float* __restrict__ vin, const int* __restrict__ rowptr,
                                                     const int* __restrict__ csr_src, const float* __restrict__ dis,
                                                     const float* __restrict__ y0, const float* __restrict__ b2,
                                                     const float* __restrict__ vmin, const float* __restrict__ vmax,
                                                     float* __restrict__ out) {
    int b = blockIdx.x & 7;
    int n = (blockIdx.x >> 3) * blockDim.x + threadIdx.x;
    if (n >= N) return;
    float a0 = 0.f, a1 = 0.f, a2 = 0.f;
    int beg = rowptr[n], end = rowptr[n + 1];
    if (beg < 0) beg = 0;
    if (end > E) end = E;
    const float* base = vin + (size_t)b * N * 3;
    for (int i = beg; i < end; ++i) {
        unsigned s = clamp_src(csr_src[i]);
        float w = dis[s];
        const float* p = base + (size_t)s * 3;
        a0 = fmaf(w, p[0], a0);
        a1 = fmaf(w, p[1], a1);
        a2 = fmaf(w, p[2], a2);
    }
    float dn = dis[n];
    size_t bn3 = ((size_t)b * N + n) * 3;
    const float* yp = y0 + bn3;
    float g0 = fmaf(a0, dn, yp[0]) + b2[0];
    float g1 = fmaf(a1, dn, yp[1]) + b2[1];
    float g2 = fmaf(a2, dn, yp[2]) + b2[2];
    float mn0 = vmin[n * 3 + 0], mx0 = vmax[n * 3 + 0];
    float mn1 = vmin[n * 3 + 1], mx1 = vmax[n * 3 + 1];
    float mn2 = vmin[n * 3 + 2], mx2 = vmax[n * 3 + 2];
    float* op = out + bn3;
    op[0] = mn0 + (mx0 - mn0) / (1.f + expf(g0));
    op[1] = mn1 + (mx1 - mn1) / (1.f + expf(g1));
    op[2] = mn2 + (mx2 - mn2) / (1.f + expf(g2));
}

// ------------------------- host launcher -------------------------

extern "C" void kernel_launch(void* const* d_in, const int* in_sizes, int n_in,
                              void* d_out, int out_size, void* d_ws, size_t ws_size,
                              hipStream_t stream) {
    const float* x      = (const float*)d_in[0];
    const int*   ei     = (const int*)d_in[1];
    const int*   rowi   = ei;
    const int*   coli   = ei + E;
    const float* vmin   = (const float*)d_in[2];
    const float* vmax   = (const float*)d_in[3];
    const float* W0     = (const float*)d_in[4];
    const float* W1     = (const float*)d_in[6];
    const float* b1v    = (const float*)d_in[7];
    const float* W2     = (const float*)d_in[8];
    const float* b2v    = (const float*)d_in[9];
    const float* gamma0 = (const float*)d_in[10];
    const float* beta0  = (const float*)d_in[11];
    const float* gamma1 = (const float*)d_in[12];
    const float* beta1  = (const float*)d_in[13];
    float* out = (float*)d_out;

    const size_t BN3  = (size_t)B * N * 3;
    const size_t H1FL = (size_t)B * N * 32;        // 12.8M fl = 51.2 MB
    const size_t UCFL = (size_t)4 * N * 32;        // 6.4M fl  = 25.6 MB
    const size_t XBFL = (size_t)B * N * 2;

    auto rnd = [](size_t nf) { return (nf + 63) & ~(size_t)63; };
    size_t off = 0;
    auto alloc = [&](size_t nfloats) -> float* {
        float* p = (float*)d_ws + off;
        off += rnd(nfloats);
        return p;
    };
    // zero-block: deg, deg_lo, cur_lo, cur_hi contiguous -> one memset
    float* deg     = alloc(N);                     // becomes dis
    int*   deg_lo  = (int*)alloc(N);
    int*   cur_lo  = (int*)alloc(N);
    int*   cur_hi  = (int*)alloc(N);
    size_t zero_bytes = (size_t)4 * rnd(N) * 4;
    int*   rowptr  = (int*)alloc(N + 1);
    int*   part    = (int*)alloc(N);
    int*   bsum    = (int*)alloc(256);
    int*   boff    = (int*)alloc(256);
    int*   csr_src = (int*)alloc(E);
    float* h1      = alloc(H1FL);

    const size_t avail_fl = ws_size / 4;
    const size_t need_full = off + 2 * H1FL + 4096;
    bool full = (avail_fl >= need_full);

    float *uA, *uB, *uC = nullptr;
    if (full) {
        uA = alloc(H1FL);
        uB = alloc(H1FL);
    } else {
        uA = alloc(UCFL);
        uB = alloc(UCFL);
        uC = alloc(UCFL);
    }
    uint2* xb1 = (uint2*)uA;
    uint2* xb2 = (uint2*)((float*)uA + XBFL);
    uint2* xb3 = (uint2*)((float*)uA + 2 * XBFL);
    float* y   = h1;
    float* v_a = h1 + rnd(4 * BN3);
    float* v_b = v_a + rnd(BN3);

    const int GE  = (E + 255) / 256;
    const int GN  = (N + 255) / 256;               // 196
    const int GB8 = GN * 8;
    const int GW  = (N * 64) / 256;
    const int NG  = (N + 127) / 128;               // 391 node groups for hopG
    dim3 blk(256);

    // CSR build
    hipMemsetAsync(deg, 0, zero_bytes, stream);
    deg2_kernel<<<GE, blk, 0, stream>>>(rowi, coli, deg, deg_lo);
    scan1_kernel<<<GN, blk, 0, stream>>>(deg, part, bsum);
    scan2_kernel<<<1, blk, 0, stream>>>(bsum, boff, GN, rowptr);
    scan3_dis_kernel<<<GN, blk, 0, stream>>>(part, boff, rowptr, deg);
    fill_kernel<<<GE, blk, 0, stream>>>(rowi, coli, rowptr, deg_lo, cur_lo, cur_hi, csr_src);
    const float* dis = deg;

    // layer 0
    xprop_kernel<false><<<GB8, blk, 0, stream>>>(x,   rowptr, csr_src, dis, xb1);
    xprop_kernel<true><<<GB8, blk, 0, stream>>>(xb1, rowptr, csr_src, dis, xb2);
    xprop_kernel<true><<<GB8, blk, 0, stream>>>(xb2, rowptr, csr_src, dis, xb3);
    build_h1_kernel<<<GW, blk, 0, stream>>>((const float4*)x, xb1, xb2, xb3, W0, gamma0, beta0, (uint4*)h1);

    const uint4* H1 = (const uint4*)h1;
    if (full) {
        hopG_kernel<0><<<NG * 8, blk, 0, stream>>>(nullptr, rowptr, csr_src, dis, H1, 0, 7, 3,
                                                   W1 + 3 * 4096, nullptr, (uint4*)uA);
        hopG_kernel<1><<<NG * 8, blk, 0, stream>>>((const unsigned*)uA, rowptr, csr_src, dis, H1, 0, 7, 3,
                                                   W1 + 2 * 4096, nullptr, (uint4*)uB);
        hopG_kernel<1><<<NG * 8, blk, 0, stream>>>((const unsigned*)uB, rowptr, csr_src, dis, H1, 0, 7, 3,
                                                   W1 + 1 * 4096, nullptr, (uint4*)uA);
        hopG_kernel<2><<<NG * 8, blk, 0, stream>>>((const unsigned*)uA, rowptr, csr_src, dis, H1, 0, 7, 3,
                                                   W1, b1v, (uint4*)uB);
        bn_project_kernel<<<GW, blk, 0, stream>>>((const uint4*)uB, (const uint4*)(uB + 4 * (size_t)N * 32),
                                                  gamma1, beta1, W2, y);
    } else {
        hopG_kernel<0><<<NG * 8, blk, 0, stream>>>(nullptr, rowptr, csr_src, dis, H1, 0, 7, 3,
                                                   W1 + 3 * 4096, nullptr, (uint4*)uA);
        // lo chunk: uA -> uC -> uA -> uC(z_lo)
        hopG_kernel<1><<<NG * 4, blk, 0, stream>>>((const unsigned*)uA, rowptr, csr_src, dis, H1, 0, 3, 2,
                                                   W1 + 2 * 4096, nullptr, (uint4*)uC);
        hopG_kernel<1><<<NG * 4, blk, 0, stream>>>((const unsigned*)uC, rowptr, csr_src, dis, H1, 0, 3, 2,
                                                   W1 + 1 * 4096, nullptr, (uint4*)uA);
        hopG_kernel<2><<<NG * 4, blk, 0, stream>>>((const unsigned*)uA, rowptr, csr_src, dis, H1, 0, 3, 2,
                                                   W1, b1v, (uint4*)uC);
        // hi chunk: uB -> uA -> uB -> uA(z_hi)
        hopG_kernel<1><<<NG * 4, blk, 0, stream>>>((const unsigned*)uB, rowptr, csr_src, dis, H1, 4, 3, 2,
                                                   W1 + 2 * 4096, nullptr, (uint4*)uA);
        hopG_kernel<1><<<NG * 4, blk, 0, stream>>>((const unsigned*)uA, rowptr, csr_src, dis, H1, 4, 3, 2,
                                                   W1 + 1 * 4096, nullptr, (uint4*)uB);
        hopG_kernel<2><<<NG * 4, blk, 0, stream>>>((const unsigned*)uB, rowptr, csr_src, dis, H1, 4, 3, 2,
                                                   W1, b1v, (uint4*)uA);
        bn_project_kernel<<<GW, blk, 0, stream>>>((const uint4*)uC, (const uint4*)uA,
                                                  gamma1, beta1, W2, y);
    }

    // layer 2 Horner at 3-dim
    qprop_kernel<<<GB8, blk, 0, stream>>>(y + 3 * BN3, rowptr, csr_src, dis, y + 2 * BN3, v_a);
    qprop_kernel<<<GB8, blk, 0, stream>>>(v_a, rowptr, csr_src, dis, y + 1 * BN3, v_b);
    qfinal_kernel<<<GB8, blk, 0, stream>>>(v_b, rowptr, csr_src, dis, y, b2v, vmin, vmax, out);
}

// Round 12
// 1506.997 us; speedup vs baseline: 1.1493x; 1.1493x over previous
//
#include <hip/hip_runtime.h>
#include <math.h>

constexpr int B = 8;
constexpr int N = 50000;
constexpr int E = 400000;
constexpr int NH = 25000;
constexpr float BN_EPS = 1e-5f;
constexpr float NEG = 0.01f;

// ------------------------- bf16 helpers -------------------------

__device__ __forceinline__ unsigned clamp_src(int s) {
    unsigned u = (unsigned)s;
    return (u < (unsigned)N) ? u : 0u;
}

__device__ __forceinline__ unsigned pack_bf16(float a, float b) {
    unsigned ua = __float_as_uint(a);
    unsigned ub = __float_as_uint(b);
    ua = (ua + 0x7FFFu + ((ua >> 16) & 1u)) >> 16;
    ub = (ub + 0x7FFFu + ((ub >> 16) & 1u)) >> 16;
    return (ub << 16) | (ua & 0xFFFFu);
}
__device__ __forceinline__ float unpack_lo(unsigned u) { return __uint_as_float(u << 16); }
__device__ __forceinline__ float unpack_hi(unsigned u) { return __uint_as_float(u & 0xFFFF0000u); }

// ------------------------- CSR construction (source-bucketed) -------------------------

__global__ __launch_bounds__(256) void deg2_kernel(const int* __restrict__ row, const int* __restrict__ col,
                                                   float* __restrict__ deg, int* __restrict__ deg_lo) {
    int e = blockIdx.x * blockDim.x + threadIdx.x;
    if (e >= E) return;
    unsigned r = clamp_src(row[e]), c = clamp_src(col[e]);
    atomicAdd(&deg[c], 1.0f);
    if (r < (unsigned)NH) atomicAdd(&deg_lo[c], 1);
}

__global__ __launch_bounds__(256) void scan1_kernel(const float* __restrict__ deg,
                                                    int* __restrict__ part, int* __restrict__ bsum) {
    __shared__ int sm[4];
    int i = blockIdx.x * blockDim.x + threadIdx.x;
    int v = (i < N) ? (int)deg[i] : 0;
    int lane = threadIdx.x & 63, wv = threadIdx.x >> 6;
    int x = v;
#pragma unroll
    for (int off = 1; off < 64; off <<= 1) {
        int t = __shfl_up(x, off);
        if (lane >= off) x += t;
    }
    if (lane == 63) sm[wv] = x;
    __syncthreads();
    int add = 0;
#pragma unroll
    for (int w = 0; w < 4; ++w) if (w < wv) add += sm[w];
    if (i < N) part[i] = x - v + add;
    if (threadIdx.x == blockDim.x - 1) bsum[blockIdx.x] = x + add;
}

__global__ __launch_bounds__(256) void scan2_kernel(const int* __restrict__ bsum, int* __restrict__ boff,
                                                    int nb, int* __restrict__ rowptr) {
    __shared__ int sm[4];
    int i = threadIdx.x;
    int v = (i < nb) ? bsum[i] : 0;
    int lane = i & 63, wv = i >> 6;
    int x = v;
#pragma unroll
    for (int off = 1; off < 64; off <<= 1) {
        int t = __shfl_up(x, off);
        if (lane >= off) x += t;
    }
    if (lane == 63) sm[wv] = x;
    __syncthreads();
    int add = 0;
#pragma unroll
    for (int w = 0; w < 4; ++w) if (w < wv) add += sm[w];
    if (i < nb) boff[i] = x - v + add;
    if (i == 0) rowptr[N] = E;
}

__global__ __launch_bounds__(256) void scan3_dis_kernel(const int* __restrict__ part, const int* __restrict__ boff,
                                                        int* __restrict__ rowptr, float* __restrict__ deg) {
    int i = blockIdx.x * blockDim.x + threadIdx.x;
    if (i < N) {
        rowptr[i] = part[i] + boff[blockIdx.x];
        float d = deg[i];
        deg[i] = (d > 0.f) ? rsqrtf(d) : 0.f;
    }
}

__global__ __launch_bounds__(256) void fill_kernel(const int* __restrict__ row, const int* __restrict__ col,
                                                   const int* __restrict__ rowptr, const int* __restrict__ deg_lo,
                                                   int* __restrict__ cur_lo, int* __restrict__ cur_hi,
                                                   int* __restrict__ csr_src) {
    int e = blockIdx.x * blockDim.x + threadIdx.x;
    if (e >= E) return;
    unsigned r = clamp_src(row[e]), c = clamp_src(col[e]);
    unsigned p;
    if (r < (unsigned)NH)
        p = (unsigned)(rowptr[c] + atomicAdd(&cur_lo[c], 1));
    else
        p = (unsigned)(rowptr[c] + deg_lo[c] + atomicAdd(&cur_hi[c], 1));
    if (p >= (unsigned)E) p = E - 1;
    csr_src[p] = (int)r;
}

// ------------------------- 4-dim propagation (layer 0), batch-pinned, bf16 out ---------

template<bool INBF>
__global__ __launch_bounds__(256) void xprop_kernel(const void* __restrict__ xin, const int* __restrict__ rowptr,
                                                    const int* __restrict__ csr_src, const float* __restrict__ dis,
                                                    uint2* __restrict__ xout) {
    int b = blockIdx.x & 7;
    int n = (blockIdx.x >> 3) * blockDim.x + threadIdx.x;
    if (n >= N) return;
    float a0 = 0.f, a1 = 0.f, a2 = 0.f, a3 = 0.f;
    int beg = rowptr[n], end = rowptr[n + 1];
    if (beg < 0) beg = 0;
    if (end > E) end = E;
    for (int i = beg; i < end; ++i) {
        unsigned s = clamp_src(csr_src[i]);
        float w = dis[s];
        if constexpr (!INBF) {
            float4 v = *((const float4*)xin + (size_t)b * N + s);
            a0 = fmaf(w, v.x, a0); a1 = fmaf(w, v.y, a1);
            a2 = fmaf(w, v.z, a2); a3 = fmaf(w, v.w, a3);
        } else {
            uint2 v = *((const uint2*)xin + (size_t)b * N + s);
            a0 = fmaf(w, unpack_lo(v.x), a0); a1 = fmaf(w, unpack_hi(v.x), a1);
            a2 = fmaf(w, unpack_lo(v.y), a2); a3 = fmaf(w, unpack_hi(v.y), a3);
        }
    }
    float dn = dis[n];
    uint2 o;
    o.x = pack_bf16(a0 * dn, a1 * dn);
    o.y = pack_bf16(a2 * dn, a3 * dn);
    xout[(size_t)b * N + n] = o;
}

// ------------------------- 16-dim concat row loader -------------------------

__device__ __forceinline__ void load_xv(const float4* __restrict__ x0, const uint2* __restrict__ x1,
                                        const uint2* __restrict__ x2, const uint2* __restrict__ x3,
                                        size_t ro, float xv[16]) {
    float4 v = x0[ro];
    xv[0] = v.x; xv[1] = v.y; xv[2] = v.z; xv[3] = v.w;
    uint2 u1 = x1[ro], u2 = x2[ro], u3 = x3[ro];
    xv[4] = unpack_lo(u1.x); xv[5] = unpack_hi(u1.x); xv[6] = unpack_lo(u1.y); xv[7] = unpack_hi(u1.y);
    xv[8] = unpack_lo(u2.x); xv[9] = unpack_hi(u2.x); xv[10] = unpack_lo(u2.y); xv[11] = unpack_hi(u2.y);
    xv[12] = unpack_lo(u3.x); xv[13] = unpack_hi(u3.x); xv[14] = unpack_lo(u3.y); xv[15] = unpack_hi(u3.y);
}

// ------------------------- build h1 = leaky(BN0([x|x1|x2|x3] @ W0)), bf16 full batch ----

__global__ __launch_bounds__(256) void build_h1_kernel(const float4* __restrict__ x0, const uint2* __restrict__ x1,
                                                       const uint2* __restrict__ x2, const uint2* __restrict__ x3,
                                                       const float* __restrict__ W0,
                                                       const float* __restrict__ gamma, const float* __restrict__ beta,
                                                       uint4* __restrict__ h1) {
    int gid = blockIdx.x * blockDim.x + threadIdx.x;
    int node = gid >> 6;
    int lane = gid & 63;
    int fg = lane >> 3, b = lane & 7;
    if (node >= N) return;
    size_t ro = (size_t)b * N + node;
    float xv[16];
    load_xv(x0, x1, x2, x3, ro, xv);
    float z[8];
#pragma unroll
    for (int j = 0; j < 8; ++j) z[j] = 0.f;
#pragma unroll
    for (int kf = 0; kf < 16; ++kf) {
        const float* wr = W0 + kf * 64 + fg * 8;
        float4 wa = *(const float4*)wr;
        float4 wb = *(const float4*)(wr + 4);
        float xs = xv[kf];
        z[0] = fmaf(xs, wa.x, z[0]); z[1] = fmaf(xs, wa.y, z[1]);
        z[2] = fmaf(xs, wa.z, z[2]); z[3] = fmaf(xs, wa.w, z[3]);
        z[4] = fmaf(xs, wb.x, z[4]); z[5] = fmaf(xs, wb.y, z[5]);
        z[6] = fmaf(xs, wb.z, z[6]); z[7] = fmaf(xs, wb.w, z[7]);
    }
    float s[8], s2[8];
#pragma unroll
    for (int j = 0; j < 8; ++j) { s[j] = z[j]; s2[j] = z[j] * z[j]; }
#pragma unroll
    for (int off = 1; off < 8; off <<= 1) {
#pragma unroll
        for (int j = 0; j < 8; ++j) {
            s[j] += __shfl_xor(s[j], off);
            s2[j] += __shfl_xor(s2[j], off);
        }
    }
    const float* gp = gamma + (size_t)node * 64 + fg * 8;
    const float* bp = beta + (size_t)node * 64 + fg * 8;
    float h[8];
#pragma unroll
    for (int j = 0; j < 8; ++j) {
        float mean = s[j] * 0.125f;
        float var = fmaf(-mean, mean, s2[j] * 0.125f);
        float rs = rsqrtf(var + BN_EPS);
        float o = fmaf(gp[j] * rs, z[j] - mean, bp[j]);
        h[j] = (o >= 0.f) ? o : NEG * o;
    }
    uint4 o;
    o.x = pack_bf16(h[0], h[1]);
    o.y = pack_bf16(h[2], h[3]);
    o.z = pack_bf16(h[4], h[5]);
    o.w = pack_bf16(h[6], h[7]);
    h1[ro * 8 + fg] = o;
}

// ------------------------- hopG: feature-half wave-split Horner hop (fixed stores) -------
// Block = 128 nodes x 2 feature-halves, 4 waves: sub = w&1 (node subgroup), half = w>>1
// (feature half, WAVE-UNIFORM -> W via SGPR broadcast). Lane owns node; gather loads its
// 64B half-row per edge (full per-lane MLP). h1 block-tile staged once via LDS (coalesced),
// dense reads h from LDS. Output packed to LDS then stored with F = j*256 + tid mapping:
// per store instruction a wave covers 1024 contiguous bytes (full lines, no RMW).

template<int MODE>
__global__ __launch_bounds__(256, 6) void hopG_kernel(const unsigned* __restrict__ u_in, const int* __restrict__ rowptr,
                                                      const int* __restrict__ csr_src, const float* __restrict__ dis,
                                                      const uint4* __restrict__ h1, int b0, int bmask, int bshift,
                                                      const float* __restrict__ Wk, const float* __restrict__ bias,
                                                      uint4* __restrict__ u_out) {
    __shared__ unsigned lds[128 * 33];
    int bl = blockIdx.x & bmask;
    int g  = blockIdx.x >> bshift;
    int tid = threadIdx.x;
    int w = tid >> 6, lane = tid & 63;
    int sub = w & 1, half = w >> 1;
    int n = g * 128 + sub * 64 + lane;
    int nc = (n < N) ? n : N - 1;
    int maxq = (N - g * 128) * 8;                 // uint4s in this block's region
    if (maxq > 1024) maxq = 1024;

    float acc[32];
#pragma unroll
    for (int c = 0; c < 32; ++c) acc[c] = 0.f;

    if constexpr (MODE > 0) {
        const uint4* U4 = (const uint4*)u_in;
        int beg = rowptr[nc], end = rowptr[nc + 1];
        if (beg < 0) beg = 0;
        if (end > E) end = E;
        if (n >= N) end = beg;
        for (int i = beg; i < end; ++i) {
            unsigned s = clamp_src(csr_src[i]);
            float wgt = dis[s];
            const uint4* ur = U4 + ((size_t)bl * N + s) * 8 + half * 4;
            uint4 r0 = ur[0], r1 = ur[1], r2 = ur[2], r3 = ur[3];
            acc[0]  = fmaf(wgt, unpack_lo(r0.x), acc[0]);  acc[1]  = fmaf(wgt, unpack_hi(r0.x), acc[1]);
            acc[2]  = fmaf(wgt, unpack_lo(r0.y), acc[2]);  acc[3]  = fmaf(wgt, unpack_hi(r0.y), acc[3]);
            acc[4]  = fmaf(wgt, unpack_lo(r0.z), acc[4]);  acc[5]  = fmaf(wgt, unpack_hi(r0.z), acc[5]);
            acc[6]  = fmaf(wgt, unpack_lo(r0.w), acc[6]);  acc[7]  = fmaf(wgt, unpack_hi(r0.w), acc[7]);
            acc[8]  = fmaf(wgt, unpack_lo(r1.x), acc[8]);  acc[9]  = fmaf(wgt, unpack_hi(r1.x), acc[9]);
            acc[10] = fmaf(wgt, unpack_lo(r1.y), acc[10]); acc[11] = fmaf(wgt, unpack_hi(r1.y), acc[11]);
            acc[12] = fmaf(wgt, unpack_lo(r1.z), acc[12]); acc[13] = fmaf(wgt, unpack_hi(r1.z), acc[13]);
            acc[14] = fmaf(wgt, unpack_lo(r1.w), acc[14]); acc[15] = fmaf(wgt, unpack_hi(r1.w), acc[15]);
            acc[16] = fmaf(wgt, unpack_lo(r2.x), acc[16]); acc[17] = fmaf(wgt, unpack_hi(r2.x), acc[17]);
            acc[18] = fmaf(wgt, unpack_lo(r2.y), acc[18]); acc[19] = fmaf(wgt, unpack_hi(r2.y), acc[19]);
            acc[20] = fmaf(wgt, unpack_lo(r2.z), acc[20]); acc[21] = fmaf(wgt, unpack_hi(r2.z), acc[21]);
            acc[22] = fmaf(wgt, unpack_lo(r2.w), acc[22]); acc[23] = fmaf(wgt, unpack_hi(r2.w), acc[23]);
            acc[24] = fmaf(wgt, unpack_lo(r3.x), acc[24]); acc[25] = fmaf(wgt, unpack_hi(r3.x), acc[25]);
            acc[26] = fmaf(wgt, unpack_lo(r3.y), acc[26]); acc[27] = fmaf(wgt, unpack_hi(r3.y), acc[27]);
            acc[28] = fmaf(wgt, unpack_lo(r3.z), acc[28]); acc[29] = fmaf(wgt, unpack_hi(r3.z), acc[29]);
            acc[30] = fmaf(wgt, unpack_lo(r3.w), acc[30]); acc[31] = fmaf(wgt, unpack_hi(r3.w), acc[31]);
        }
        float dn = dis[nc];
#pragma unroll
        for (int c = 0; c < 32; ++c) acc[c] *= dn;
    }
    if constexpr (MODE == 2) {
        const float* bp = bias + half * 32;
#pragma unroll
        for (int c = 0; c < 32; ++c) acc[c] += bp[c];
    }

    // stage h1 block-tile -> LDS (coalesced: per instruction, wave covers 1024B)
    {
        const uint4* hsrc = h1 + ((size_t)(b0 + bl) * N + (size_t)g * 128) * 8;
#pragma unroll
        for (int j = 0; j < 4; ++j) {
            int F = j * 256 + tid;
            if (F < maxq) {
                uint4 v = hsrc[F];
                unsigned* Ld = lds + (F >> 3) * 33 + (F & 7) * 4;
                Ld[0] = v.x; Ld[1] = v.y; Ld[2] = v.z; Ld[3] = v.w;
            }
        }
    }
    __syncthreads();

    // dense: h row from LDS, W column-slice wave-uniform (SGPR broadcast)
    {
        const unsigned* Lr = lds + (sub * 64 + lane) * 33;
#pragma unroll 2
        for (int kk = 0; kk < 8; ++kk) {
            unsigned hs[4] = {Lr[kk * 4 + 0], Lr[kk * 4 + 1], Lr[kk * 4 + 2], Lr[kk * 4 + 3]};
#pragma unroll
            for (int t = 0; t < 4; ++t) {
                int k = kk * 8 + t * 2;
                float h0 = unpack_lo(hs[t]);
                float h1f = unpack_hi(hs[t]);
                const float* w0 = Wk + k * 64 + half * 32;
                const float* w1 = w0 + 64;
#pragma unroll
                for (int c = 0; c < 32; ++c) acc[c] = fmaf(h0, w0[c], acc[c]);
#pragma unroll
                for (int c = 0; c < 32; ++c) acc[c] = fmaf(h1f, w1[c], acc[c]);
            }
        }
    }
    __syncthreads();

    // pack -> LDS
    {
        unsigned* Lr = lds + (sub * 64 + lane) * 33 + half * 16;
#pragma unroll
        for (int q = 0; q < 16; ++q)
            Lr[q] = pack_bf16(acc[2 * q], acc[2 * q + 1]);
    }
    __syncthreads();

    // coalesced store: instruction j -> wave writes 64 consecutive uint4 (1024B)
    {
        uint4* ob = u_out + ((size_t)bl * N + (size_t)g * 128) * 8;
#pragma unroll
        for (int j = 0; j < 4; ++j) {
            int F = j * 256 + tid;
            if (F < maxq) {
                const unsigned* Ls = lds + (F >> 3) * 33 + (F & 7) * 4;
                uint4 v;
                v.x = Ls[0]; v.y = Ls[1]; v.z = Ls[2]; v.w = Ls[3];
                ob[F] = v;
            }
        }
    }
}

// ------------------------- BN1 + leaky + W2 projection (ILP rounds) -------------------------

__global__ __launch_bounds__(256) void bn_project_kernel(const uint4* __restrict__ zlo, const uint4* __restrict__ zhi,
                                                         const float* __restrict__ gamma, const float* __restrict__ beta,
                                                         const float* __restrict__ W2, float* __restrict__ y) {
    int gid = blockIdx.x * blockDim.x + threadIdx.x;
    int node = gid >> 6;
    int lane = gid & 63;
    int fg = lane >> 3, b = lane & 7;
    if (node >= N) return;
    const uint4* zp = (b < 4) ? (zlo + ((size_t)b * N + node) * 8)
                              : (zhi + ((size_t)(b - 4) * N + node) * 8);
    uint4 v = zp[fg];
    float h[8] = {unpack_lo(v.x), unpack_hi(v.x), unpack_lo(v.y), unpack_hi(v.y),
                  unpack_lo(v.z), unpack_hi(v.z), unpack_lo(v.w), unpack_hi(v.w)};
    float s[8], s2[8];
#pragma unroll
    for (int j = 0; j < 8; ++j) { s[j] = h[j]; s2[j] = h[j] * h[j]; }
#pragma unroll
    for (int off = 1; off < 8; off <<= 1) {
#pragma unroll
        for (int j = 0; j < 8; ++j) {
            s[j] += __shfl_xor(s[j], off);
            s2[j] += __shfl_xor(s2[j], off);
        }
    }
    const float* gp = gamma + (size_t)node * 64 + fg * 8;
    const float* bp = beta + (size_t)node * 64 + fg * 8;
#pragma unroll
    for (int j = 0; j < 8; ++j) {
        float mean = s[j] * 0.125f;
        float var = fmaf(-mean, mean, s2[j] * 0.125f);
        float rs = rsqrtf(var + BN_EPS);
        float o = fmaf(gp[j] * rs, h[j] - mean, bp[j]);
        h[j] = (o >= 0.f) ? o : NEG * o;
    }
    float p[12];
#pragma unroll
    for (int k = 0; k < 4; ++k) {
#pragma unroll
        for (int c = 0; c < 3; ++c) {
            float sv = 0.f;
#pragma unroll
            for (int j = 0; j < 8; ++j)
                sv = fmaf(h[j], W2[k * 192 + (fg * 8 + j) * 3 + c], sv);
            p[k * 3 + c] = sv;
        }
    }
#pragma unroll
    for (int t = 8; t < 64; t <<= 1) {
#pragma unroll
        for (int i = 0; i < 12; ++i)
            p[i] += __shfl_xor(p[i], t);
    }
    if (fg == 0) {
        size_t bn3 = ((size_t)b * N + node) * 3;
#pragma unroll
        for (int k = 0; k < 4; ++k)
#pragma unroll
            for (int c = 0; c < 3; ++c)
                y[(size_t)k * B * N * 3 + bn3 + c] = p[k * 3 + c];
    }
}

// ------------------------- 3-dim propagation (layer 2 Horner) -------------------------

__global__ __launch_bounds__(256) void qprop_kernel(const float* __restrict__ vin, const int* __restrict__ rowptr,
                                                    const int* __restrict__ csr_src, const float* __restrict__ dis,
                                                    const float* __restrict__ add, float* __restrict__ vout) {
    int b = blockIdx.x & 7;
    int n = (blockIdx.x >> 3) * blockDim.x + threadIdx.x;
    if (n >= N) return;
    float a0 = 0.f, a1 = 0.f, a2 = 0.f;
    int beg = rowptr[n], end = rowptr[n + 1];
    if (beg < 0) beg = 0;
    if (end > E) end = E;
    const float* base = vin + (size_t)b * N * 3;
    for (int i = beg; i < end; ++i) {
        unsigned s = clamp_src(csr_src[i]);
        float w = dis[s];
        const float* p = base + (size_t)s * 3;
        a0 = fmaf(w, p[0], a0);
        a1 = fmaf(w, p[1], a1);
        a2 = fmaf(w, p[2], a2);
    }
    float dn = dis[n];
    const float* ap = add + ((size_t)b * N + n) * 3;
    float* op = vout + ((size_t)b * N + n) * 3;
    op[0] = fmaf(a0, dn, ap[0]);
    op[1] = fmaf(a1, dn, ap[1]);
    op[2] = fmaf(a2, dn, ap[2]);
}

__global__ __launch_bounds__(256) void qfinal_kernel(const float* __restrict__ vin, const int* __restrict__ rowptr,
                                                     const int* __restrict__ csr_src, const float* __restrict__ dis,
                                                     const float* __restrict__ y0, const float* __restrict__ b2,
                                                     const float* __restrict__ vmin, const float* __restrict__ vmax,
                                                     float* __restrict__ out) {
    int b = blockIdx.x & 7;
    int n = (blockIdx.x >> 3) * blockDim.x + threadIdx.x;
    if (n >= N) return;
    float a0 = 0.f, a1 = 0.f, a2 = 0.f;
    int beg = rowptr[n], end = rowptr[n + 1];
    if (beg < 0) beg = 0;
    if (end > E) end = E;
    const float* base = vin + (size_t)b * N * 3;
    for (int i = beg; i < end; ++i) {
        unsigned s = clamp_src(csr_src[i]);
        float w = dis[s];
        const float* p = base + (size_t)s * 3;
        a0 = fmaf(w, p[0], a0);
        a1 = fmaf(w, p[1], a1);
        a2 = fmaf(w, p[2], a2);
    }
    float dn = dis[n];
    size_t bn3 = ((size_t)b * N + n) * 3;
    const float* yp = y0 + bn3;
    float g0 = fmaf(a0, dn, yp[0]) + b2[0];
    float g1 = fmaf(a1, dn, yp[1]) + b2[1];
    float g2 = fmaf(a2, dn, yp[2]) + b2[2];
    float mn0 = vmin[n * 3 + 0], mx0 = vmax[n * 3 + 0];
    float mn1 = vmin[n * 3 + 1], mx1 = vmax[n * 3 + 1];
    float mn2 = vmin[n * 3 + 2], mx2 = vmax[n * 3 + 2];
    float* op = out + bn3;
    op[0] = mn0 + (mx0 - mn0) / (1.f + expf(g0));
    op[1] = mn1 + (mx1 - mn1) / (1.f + expf(g1));
    op[2] = mn2 + (mx2 - mn2) / (1.f + expf(g2));
}

// ------------------------- host launcher -------------------------

extern "C" void kernel_launch(void* const* d_in, const int* in_sizes, int n_in,
                              void* d_out, int out_size, void* d_ws, size_t ws_size,
                              hipStream_t stream) {
    const float* x      = (const float*)d_in[0];
    const int*   ei     = (const int*)d_in[1];
    const int*   rowi   = ei;
    const int*   coli   = ei + E;
    const float* vmin   = (const float*)d_in[2];
    const float* vmax   = (const float*)d_in[3];
    const float* W0     = (const float*)d_in[4];
    const float* W1     = (const float*)d_in[6];
    const float* b1v    = (const float*)d_in[7];
    const float* W2     = (const float*)d_in[8];
    const float* b2v    = (const float*)d_in[9];
    const float* gamma0 = (const float*)d_in[10];
    const float* beta0  = (const float*)d_in[11];
    const float* gamma1 = (const float*)d_in[12];
    const float* beta1  = (const float*)d_in[13];
    float* out = (float*)d_out;

    const size_t BN3  = (size_t)B * N * 3;
    const size_t H1FL = (size_t)B * N * 32;        // 12.8M fl = 51.2 MB
    const size_t UCFL = (size_t)4 * N * 32;        // 6.4M fl  = 25.6 MB
    const size_t XBFL = (size_t)B * N * 2;

    auto rnd = [](size_t nf) { return (nf + 63) & ~(size_t)63; };
    size_t off = 0;
    auto alloc = [&](size_t nfloats) -> float* {
        float* p = (float*)d_ws + off;
        off += rnd(nfloats);
        return p;
    };
    // zero-block: deg, deg_lo, cur_lo, cur_hi contiguous -> one memset
    float* deg     = alloc(N);                     // becomes dis
    int*   deg_lo  = (int*)alloc(N);
    int*   cur_lo  = (int*)alloc(N);
    int*   cur_hi  = (int*)alloc(N);
    size_t zero_bytes = (size_t)4 * rnd(N) * 4;
    int*   rowptr  = (int*)alloc(N + 1);
    int*   part    = (int*)alloc(N);
    int*   bsum    = (int*)alloc(256);
    int*   boff    = (int*)alloc(256);
    int*   csr_src = (int*)alloc(E);
    float* h1      = alloc(H1FL);

    const size_t avail_fl = ws_size / 4;
    const size_t need_full = off + 2 * H1FL + 4096;
    bool full = (avail_fl >= need_full);

    float *uA, *uB, *uC = nullptr;
    if (full) {
        uA = alloc(H1FL);
        uB = alloc(H1FL);
    } else {
        uA = alloc(UCFL);
        uB = alloc(UCFL);
        uC = alloc(UCFL);
    }
    uint2* xb1 = (uint2*)uA;
    uint2* xb2 = (uint2*)((float*)uA + XBFL);
    uint2* xb3 = (uint2*)((float*)uA + 2 * XBFL);
    float* y   = h1;
    float* v_a = h1 + rnd(4 * BN3);
    float* v_b = v_a + rnd(BN3);

    const int GE  = (E + 255) / 256;
    const int GN  = (N + 255) / 256;               // 196
    const int GB8 = GN * 8;
    const int GW  = (N * 64) / 256;
    const int NG  = (N + 127) / 128;               // 391 node groups for hopG
    dim3 blk(256);

    // CSR build
    hipMemsetAsync(deg, 0, zero_bytes, stream);
    deg2_kernel<<<GE, blk, 0, stream>>>(rowi, coli, deg, deg_lo);
    scan1_kernel<<<GN, blk, 0, stream>>>(deg, part, bsum);
    scan2_kernel<<<1, blk, 0, stream>>>(bsum, boff, GN, rowptr);
    scan3_dis_kernel<<<GN, blk, 0, stream>>>(part, boff, rowptr, deg);
    fill_kernel<<<GE, blk, 0, stream>>>(rowi, coli, rowptr, deg_lo, cur_lo, cur_hi, csr_src);
    const float* dis = deg;

    // layer 0
    xprop_kernel<false><<<GB8, blk, 0, stream>>>(x,   rowptr, csr_src, dis, xb1);
    xprop_kernel<true><<<GB8, blk, 0, stream>>>(xb1, rowptr, csr_src, dis, xb2);
    xprop_kernel<true><<<GB8, blk, 0, stream>>>(xb2, rowptr, csr_src, dis, xb3);
    build_h1_kernel<<<GW, blk, 0, stream>>>((const float4*)x, xb1, xb2, xb3, W0, gamma0, beta0, (uint4*)h1);

    const uint4* H1 = (const uint4*)h1;
    if (full) {
        hopG_kernel<0><<<NG * 8, blk, 0, stream>>>(nullptr, rowptr, csr_src, dis, H1, 0, 7, 3,
                                                   W1 + 3 * 4096, nullptr, (uint4*)uA);
        hopG_kernel<1><<<NG * 8, blk, 0, stream>>>((const unsigned*)uA, rowptr, csr_src, dis, H1, 0, 7, 3,
                                                   W1 + 2 * 4096, nullptr, (uint4*)uB);
        hopG_kernel<1><<<NG * 8, blk, 0, stream>>>((const unsigned*)uB, rowptr, csr_src, dis, H1, 0, 7, 3,
                                                   W1 + 1 * 4096, nullptr, (uint4*)uA);
        hopG_kernel<2><<<NG * 8, blk, 0, stream>>>((const unsigned*)uA, rowptr, csr_src, dis, H1, 0, 7, 3,
                                                   W1, b1v, (uint4*)uB);
        bn_project_kernel<<<GW, blk, 0, stream>>>((const uint4*)uB, (const uint4*)(uB + 4 * (size_t)N * 32),
                                                  gamma1, beta1, W2, y);
    } else {
        hopG_kernel<0><<<NG * 8, blk, 0, stream>>>(nullptr, rowptr, csr_src, dis, H1, 0, 7, 3,
                                                   W1 + 3 * 4096, nullptr, (uint4*)uA);
        // lo chunk: uA -> uC -> uA -> uC(z_lo)
        hopG_kernel<1><<<NG * 4, blk, 0, stream>>>((const unsigned*)uA, rowptr, csr_src, dis, H1, 0, 3, 2,
                                                   W1 + 2 * 4096, nullptr, (uint4*)uC);
        hopG_kernel<1><<<NG * 4, blk, 0, stream>>>((const unsigned*)uC, rowptr, csr_src, dis, H1, 0, 3, 2,
                                                   W1 + 1 * 4096, nullptr, (uint4*)uA);
        hopG_kernel<2><<<NG * 4, blk, 0, stream>>>((const unsigned*)uA, rowptr, csr_src, dis, H1, 0, 3, 2,
                                                   W1, b1v, (uint4*)uC);
        // hi chunk: uB -> uA -> uB -> uA(z_hi)
        hopG_kernel<1><<<NG * 4, blk, 0, stream>>>((const unsigned*)uB, rowptr, csr_src, dis, H1, 4, 3, 2,
                                                   W1 + 2 * 4096, nullptr, (uint4*)uA);
        hopG_kernel<1><<<NG * 4, blk, 0, stream>>>((const unsigned*)uA, rowptr, csr_src, dis, H1, 4, 3, 2,
                                                   W1 + 1 * 4096, nullptr, (uint4*)uB);
        hopG_kernel<2><<<NG * 4, blk, 0, stream>>>((const unsigned*)uB, rowptr, csr_src, dis, H1, 4, 3, 2,
                                                   W1, b1v, (uint4*)uA);
        bn_project_kernel<<<GW, blk, 0, stream>>>((const uint4*)uC, (const uint4*)uA,
                                                  gamma1, beta1, W2, y);
    }

    // layer 2 Horner at 3-dim
    qprop_kernel<<<GB8, blk, 0, stream>>>(y + 3 * BN3, rowptr, csr_src, dis, y + 2 * BN3, v_a);
    qprop_kernel<<<GB8, blk, 0, stream>>>(v_a, rowptr, csr_src, dis, y + 1 * BN3, v_b);
    qfinal_kernel<<<GB8, blk, 0, stream>>>(v_b, rowptr, csr_src, dis, y, b2v, vmin, vmax, out);
}

// Round 13
// 1283.089 us; speedup vs baseline: 1.3499x; 1.1745x over previous
//
#include <hip/hip_runtime.h>
#include <math.h>

constexpr int B = 8;
constexpr int N = 50000;
constexpr int E = 400000;
constexpr float BN_EPS = 1e-5f;
constexpr float NEG = 0.01f;

// ------------------------- bf16 helpers -------------------------

__device__ __forceinline__ unsigned clamp_src(int s) {
    unsigned u = (unsigned)s;
    return (u < (unsigned)N) ? u : 0u;
}

__device__ __forceinline__ unsigned pack_bf16(float a, float b) {
    unsigned ua = __float_as_uint(a);
    unsigned ub = __float_as_uint(b);
    ua = (ua + 0x7FFFu + ((ua >> 16) & 1u)) >> 16;
    ub = (ub + 0x7FFFu + ((ub >> 16) & 1u)) >> 16;
    return (ub << 16) | (ua & 0xFFFFu);
}
__device__ __forceinline__ float unpack_lo(unsigned u) { return __uint_as_float(u << 16); }
__device__ __forceinline__ float unpack_hi(unsigned u) { return __uint_as_float(u & 0xFFFF0000u); }

__device__ __forceinline__ void store_row64_bf(uint4* p, const float acc[64]) {
#pragma unroll
    for (int q = 0; q < 8; ++q) {
        uint4 v;
        v.x = pack_bf16(acc[q * 8 + 0], acc[q * 8 + 1]);
        v.y = pack_bf16(acc[q * 8 + 2], acc[q * 8 + 3]);
        v.z = pack_bf16(acc[q * 8 + 4], acc[q * 8 + 5]);
        v.w = pack_bf16(acc[q * 8 + 6], acc[q * 8 + 7]);
        p[q] = v;
    }
}

// ------------------------- CSR construction -------------------------

__global__ __launch_bounds__(256) void deg_kernel(const int* __restrict__ col, float* __restrict__ deg) {
    int e = blockIdx.x * blockDim.x + threadIdx.x;
    if (e < E) atomicAdd(&deg[clamp_src(col[e])], 1.0f);
}

__global__ __launch_bounds__(256) void scan1_kernel(const float* __restrict__ deg,
                                                    int* __restrict__ part, int* __restrict__ bsum) {
    __shared__ int sm[4];
    int i = blockIdx.x * blockDim.x + threadIdx.x;
    int v = (i < N) ? (int)deg[i] : 0;
    int lane = threadIdx.x & 63, wv = threadIdx.x >> 6;
    int x = v;
#pragma unroll
    for (int off = 1; off < 64; off <<= 1) {
        int t = __shfl_up(x, off);
        if (lane >= off) x += t;
    }
    if (lane == 63) sm[wv] = x;
    __syncthreads();
    int add = 0;
#pragma unroll
    for (int w = 0; w < 4; ++w) if (w < wv) add += sm[w];
    if (i < N) part[i] = x - v + add;
    if (threadIdx.x == blockDim.x - 1) bsum[blockIdx.x] = x + add;
}

__global__ __launch_bounds__(256) void scan2_kernel(const int* __restrict__ bsum, int* __restrict__ boff,
                                                    int nb, int* __restrict__ rowptr) {
    __shared__ int sm[4];
    int i = threadIdx.x;
    int v = (i < nb) ? bsum[i] : 0;
    int lane = i & 63, wv = i >> 6;
    int x = v;
#pragma unroll
    for (int off = 1; off < 64; off <<= 1) {
        int t = __shfl_up(x, off);
        if (lane >= off) x += t;
    }
    if (lane == 63) sm[wv] = x;
    __syncthreads();
    int add = 0;
#pragma unroll
    for (int w = 0; w < 4; ++w) if (w < wv) add += sm[w];
    if (i < nb) boff[i] = x - v + add;
    if (i == 0) rowptr[N] = E;
}

__global__ __launch_bounds__(256) void scan3_kernel(const int* __restrict__ part, const int* __restrict__ boff,
                                                    int* __restrict__ rowptr) {
    int i = blockIdx.x * blockDim.x + threadIdx.x;
    if (i < N) rowptr[i] = part[i] + boff[blockIdx.x];
}

__global__ __launch_bounds__(256) void fill_kernel(const int* __restrict__ row, const int* __restrict__ col,
                                                   const int* __restrict__ rowptr,
                                                   int* __restrict__ cursor, int* __restrict__ csr_src) {
    int e = blockIdx.x * blockDim.x + threadIdx.x;
    if (e >= E) return;
    unsigned r = clamp_src(row[e]), c = clamp_src(col[e]);
    unsigned p = (unsigned)(rowptr[c] + atomicAdd(&cursor[c], 1));
    if (p >= (unsigned)E) p = E - 1;
    csr_src[p] = (int)r;
}

// ------------------------- degree-uniform permutation (counting sort by degree) --------

__global__ __launch_bounds__(256) void hist_kernel(const float* __restrict__ deg, int* __restrict__ hist) {
    int i = blockIdx.x * blockDim.x + threadIdx.x;
    if (i < N) {
        int d = (int)deg[i];
        if (d > 1023) d = 1023;
        atomicAdd(&hist[d], 1);
    }
}

// exclusive scan of 1024 bins (single 256-thread block, 4 bins/thread)
__global__ __launch_bounds__(256) void hscan_kernel(const int* __restrict__ hist, int* __restrict__ binstart) {
    __shared__ int sm[4];
    int t = threadIdx.x;
    int h0 = hist[t * 4 + 0], h1 = hist[t * 4 + 1], h2 = hist[t * 4 + 2], h3 = hist[t * 4 + 3];
    int sum = h0 + h1 + h2 + h3;
    int lane = t & 63, wv = t >> 6;
    int x = sum;
#pragma unroll
    for (int off = 1; off < 64; off <<= 1) {
        int v = __shfl_up(x, off);
        if (lane >= off) x += v;
    }
    if (lane == 63) sm[wv] = x;
    __syncthreads();
    int add = 0;
#pragma unroll
    for (int w = 0; w < 4; ++w) if (w < wv) add += sm[w];
    int excl = x - sum + add;
    binstart[t * 4 + 0] = excl;
    binstart[t * 4 + 1] = excl + h0;
    binstart[t * 4 + 2] = excl + h0 + h1;
    binstart[t * 4 + 3] = excl + h0 + h1 + h2;
}

// rank nodes by degree -> perm; also deg -> dis in place
__global__ __launch_bounds__(256) void rank_dis_kernel(float* __restrict__ deg, const int* __restrict__ binstart,
                                                       int* __restrict__ bincur, int* __restrict__ perm) {
    int n = blockIdx.x * blockDim.x + threadIdx.x;
    if (n >= N) return;
    float d = deg[n];
    int di = (int)d;
    if (di > 1023) di = 1023;
    int r = binstart[di] + atomicAdd(&bincur[di], 1);
    if ((unsigned)r < (unsigned)N) perm[r] = n;
    deg[n] = (d > 0.f) ? rsqrtf(d) : 0.f;
}

// ------------------------- 4-dim propagation (layer 0), batch-pinned, bf16 out ---------

template<bool INBF>
__global__ __launch_bounds__(256) void xprop_kernel(const void* __restrict__ xin, const int* __restrict__ rowptr,
                                                    const int* __restrict__ csr_src, const float* __restrict__ dis,
                                                    uint2* __restrict__ xout) {
    int b = blockIdx.x & 7;
    int n = (blockIdx.x >> 3) * blockDim.x + threadIdx.x;
    if (n >= N) return;
    float a0 = 0.f, a1 = 0.f, a2 = 0.f, a3 = 0.f;
    int beg = rowptr[n], end = rowptr[n + 1];
    if (beg < 0) beg = 0;
    if (end > E) end = E;
    for (int i = beg; i < end; ++i) {
        unsigned s = clamp_src(csr_src[i]);
        float w = dis[s];
        if constexpr (!INBF) {
            float4 v = *((const float4*)xin + (size_t)b * N + s);
            a0 = fmaf(w, v.x, a0); a1 = fmaf(w, v.y, a1);
            a2 = fmaf(w, v.z, a2); a3 = fmaf(w, v.w, a3);
        } else {
            uint2 v = *((const uint2*)xin + (size_t)b * N + s);
            a0 = fmaf(w, unpack_lo(v.x), a0); a1 = fmaf(w, unpack_hi(v.x), a1);
            a2 = fmaf(w, unpack_lo(v.y), a2); a3 = fmaf(w, unpack_hi(v.y), a3);
        }
    }
    float dn = dis[n];
    uint2 o;
    o.x = pack_bf16(a0 * dn, a1 * dn);
    o.y = pack_bf16(a2 * dn, a3 * dn);
    xout[(size_t)b * N + n] = o;
}

// ------------------------- 16-dim concat row loader -------------------------

__device__ __forceinline__ void load_xv(const float4* __restrict__ x0, const uint2* __restrict__ x1,
                                        const uint2* __restrict__ x2, const uint2* __restrict__ x3,
                                        size_t ro, float xv[16]) {
    float4 v = x0[ro];
    xv[0] = v.x; xv[1] = v.y; xv[2] = v.z; xv[3] = v.w;
    uint2 u1 = x1[ro], u2 = x2[ro], u3 = x3[ro];
    xv[4] = unpack_lo(u1.x); xv[5] = unpack_hi(u1.x); xv[6] = unpack_lo(u1.y); xv[7] = unpack_hi(u1.y);
    xv[8] = unpack_lo(u2.x); xv[9] = unpack_hi(u2.x); xv[10] = unpack_lo(u2.y); xv[11] = unpack_hi(u2.y);
    xv[12] = unpack_lo(u3.x); xv[13] = unpack_hi(u3.x); xv[14] = unpack_lo(u3.y); xv[15] = unpack_hi(u3.y);
}

// ------------------------- build h1 = leaky(BN0([x|x1|x2|x3] @ W0)), bf16 full batch ----

__global__ __launch_bounds__(256) void build_h1_kernel(const float4* __restrict__ x0, const uint2* __restrict__ x1,
                                                       const uint2* __restrict__ x2, const uint2* __restrict__ x3,
                                                       const float* __restrict__ W0,
                                                       const float* __restrict__ gamma, const float* __restrict__ beta,
                                                       uint4* __restrict__ h1) {
    int gid = blockIdx.x * blockDim.x + threadIdx.x;
    int node = gid >> 6;
    int lane = gid & 63;
    int fg = lane >> 3, b = lane & 7;
    if (node >= N) return;
    size_t ro = (size_t)b * N + node;
    float xv[16];
    load_xv(x0, x1, x2, x3, ro, xv);
    float z[8];
#pragma unroll
    for (int j = 0; j < 8; ++j) z[j] = 0.f;
#pragma unroll
    for (int kf = 0; kf < 16; ++kf) {
        const float* wr = W0 + kf * 64 + fg * 8;
        float4 wa = *(const float4*)wr;
        float4 wb = *(const float4*)(wr + 4);
        float xs = xv[kf];
        z[0] = fmaf(xs, wa.x, z[0]); z[1] = fmaf(xs, wa.y, z[1]);
        z[2] = fmaf(xs, wa.z, z[2]); z[3] = fmaf(xs, wa.w, z[3]);
        z[4] = fmaf(xs, wb.x, z[4]); z[5] = fmaf(xs, wb.y, z[5]);
        z[6] = fmaf(xs, wb.z, z[6]); z[7] = fmaf(xs, wb.w, z[7]);
    }
    float s[8], s2[8];
#pragma unroll
    for (int j = 0; j < 8; ++j) { s[j] = z[j]; s2[j] = z[j] * z[j]; }
#pragma unroll
    for (int off = 1; off < 8; off <<= 1) {
#pragma unroll
        for (int j = 0; j < 8; ++j) {
            s[j] += __shfl_xor(s[j], off);
            s2[j] += __shfl_xor(s2[j], off);
        }
    }
    const float* gp = gamma + (size_t)node * 64 + fg * 8;
    const float* bp = beta + (size_t)node * 64 + fg * 8;
    float h[8];
#pragma unroll
    for (int j = 0; j < 8; ++j) {
        float mean = s[j] * 0.125f;
        float var = fmaf(-mean, mean, s2[j] * 0.125f);
        float rs = rsqrtf(var + BN_EPS);
        float o = fmaf(gp[j] * rs, z[j] - mean, bp[j]);
        h[j] = (o >= 0.f) ? o : NEG * o;
    }
    uint4 o;
    o.x = pack_bf16(h[0], h[1]);
    o.y = pack_bf16(h[2], h[3]);
    o.z = pack_bf16(h[4], h[5]);
    o.w = pack_bf16(h[6], h[7]);
    h1[ro * 8 + fg] = o;
}

// ------------------------- bf16 gather (pair-pipelined) + dense 64x64 -------------------

__device__ __forceinline__ void fma_row(float acc[64], float w, const uint4 r[8]) {
#pragma unroll
    for (int q = 0; q < 8; ++q) {
        uint4 v = r[q];
        acc[q * 8 + 0] = fmaf(w, unpack_lo(v.x), acc[q * 8 + 0]);
        acc[q * 8 + 1] = fmaf(w, unpack_hi(v.x), acc[q * 8 + 1]);
        acc[q * 8 + 2] = fmaf(w, unpack_lo(v.y), acc[q * 8 + 2]);
        acc[q * 8 + 3] = fmaf(w, unpack_hi(v.y), acc[q * 8 + 3]);
        acc[q * 8 + 4] = fmaf(w, unpack_lo(v.z), acc[q * 8 + 4]);
        acc[q * 8 + 5] = fmaf(w, unpack_hi(v.z), acc[q * 8 + 5]);
        acc[q * 8 + 6] = fmaf(w, unpack_lo(v.w), acc[q * 8 + 6]);
        acc[q * 8 + 7] = fmaf(w, unpack_hi(v.w), acc[q * 8 + 7]);
    }
}

__device__ __forceinline__ void gather64_bf(const uint4* __restrict__ ub8, int beg, int end,
                                            const int* __restrict__ csr_src, const float* __restrict__ dis,
                                            float acc[64]) {
    if (beg < 0) beg = 0;
    if (end > E) end = E;
    int i = beg;
    for (; i + 1 < end; i += 2) {
        unsigned s0 = clamp_src(csr_src[i]);
        unsigned s1 = clamp_src(csr_src[i + 1]);
        float w0 = dis[s0], w1 = dis[s1];
        const uint4* p0 = ub8 + (size_t)s0 * 8;
        const uint4* p1 = ub8 + (size_t)s1 * 8;
        uint4 r0[8], r1[8];
#pragma unroll
        for (int q = 0; q < 8; ++q) r0[q] = p0[q];
#pragma unroll
        for (int q = 0; q < 8; ++q) r1[q] = p1[q];
        fma_row(acc, w0, r0);
        fma_row(acc, w1, r1);
    }
    if (i < end) {
        unsigned s0 = clamp_src(csr_src[i]);
        float w0 = dis[s0];
        const uint4* p0 = ub8 + (size_t)s0 * 8;
        uint4 r0[8];
#pragma unroll
        for (int q = 0; q < 8; ++q) r0[q] = p0[q];
        fma_row(acc, w0, r0);
    }
}

__device__ __forceinline__ void dense64_bf(const uint4* __restrict__ hp8, const float* __restrict__ W, float acc[64]) {
#pragma unroll 1
    for (int kk = 0; kk < 4; ++kk) {
        float hreg[16];
        uint4 va = hp8[kk * 2], vb = hp8[kk * 2 + 1];
        hreg[0] = unpack_lo(va.x); hreg[1] = unpack_hi(va.x);
        hreg[2] = unpack_lo(va.y); hreg[3] = unpack_hi(va.y);
        hreg[4] = unpack_lo(va.z); hreg[5] = unpack_hi(va.z);
        hreg[6] = unpack_lo(va.w); hreg[7] = unpack_hi(va.w);
        hreg[8] = unpack_lo(vb.x); hreg[9] = unpack_hi(vb.x);
        hreg[10] = unpack_lo(vb.y); hreg[11] = unpack_hi(vb.y);
        hreg[12] = unpack_lo(vb.z); hreg[13] = unpack_hi(vb.z);
        hreg[14] = unpack_lo(vb.w); hreg[15] = unpack_hi(vb.w);
        const float* Wp = W + kk * 16 * 64;
#pragma unroll
        for (int k = 0; k < 16; ++k) {
            float hv = hreg[k];
#pragma unroll
            for (int c = 0; c < 64; ++c)
                acc[c] = fmaf(hv, Wp[k * 64 + c], acc[c]);
        }
    }
}

// ------------------------- Horner hop (thread = full row; degree-sorted for MODE>0) -----
// MODE 0: u_out = h1@Wk (linear node order). MODE >0: thread r handles node perm[r]
// (degree-uniform waves), u_out = dis_n*(A' u_in) + h1@Wk (+ bias for MODE 2).

template<int MODE>
__global__ __launch_bounds__(256) void hopM_kernel(const uint4* __restrict__ u_in, const int* __restrict__ rowptr,
                                                   const int* __restrict__ csr_src, const float* __restrict__ dis,
                                                   const int* __restrict__ perm,
                                                   const uint4* __restrict__ h1, int b0, int bmask, int bshift,
                                                   const float* __restrict__ Wk, const float* __restrict__ bias,
                                                   uint4* __restrict__ u_out) {
    int bl = blockIdx.x & bmask;
    int r = (blockIdx.x >> bshift) * blockDim.x + threadIdx.x;
    if (r >= N) return;
    int n;
    if constexpr (MODE > 0) n = (int)clamp_src(perm[r]);
    else n = r;
    float acc[64];
#pragma unroll
    for (int f = 0; f < 64; ++f) acc[f] = 0.f;
    if constexpr (MODE > 0) {
        gather64_bf(u_in + (size_t)bl * N * 8, rowptr[n], rowptr[n + 1], csr_src, dis, acc);
        float dn = dis[n];
#pragma unroll
        for (int f = 0; f < 64; ++f) acc[f] *= dn;
    }
    if constexpr (MODE == 2) {
#pragma unroll
        for (int f = 0; f < 64; ++f) acc[f] += bias[f];
    }
    dense64_bf(h1 + ((size_t)(b0 + bl) * N + n) * 8, Wk, acc);
    store_row64_bf(u_out + ((size_t)bl * N + n) * 8, acc);
}

// ------------------------- BN1 + leaky + W2 projection -------------------------

__global__ __launch_bounds__(256) void bn_project_kernel(const uint4* __restrict__ zlo, const uint4* __restrict__ zhi,
                                                         const float* __restrict__ gamma, const float* __restrict__ beta,
                                                         const float* __restrict__ W2, float* __restrict__ y) {
    int gid = blockIdx.x * blockDim.x + threadIdx.x;
    int node = gid >> 6;
    int lane = gid & 63;
    int fg = lane >> 3, b = lane & 7;
    if (node >= N) return;
    const uint4* zp = (b < 4) ? (zlo + ((size_t)b * N + node) * 8)
                              : (zhi + ((size_t)(b - 4) * N + node) * 8);
    uint4 v = zp[fg];
    float h[8] = {unpack_lo(v.x), unpack_hi(v.x), unpack_lo(v.y), unpack_hi(v.y),
                  unpack_lo(v.z), unpack_hi(v.z), unpack_lo(v.w), unpack_hi(v.w)};
    float s[8], s2[8];
#pragma unroll
    for (int j = 0; j < 8; ++j) { s[j] = h[j]; s2[j] = h[j] * h[j]; }
#pragma unroll
    for (int off = 1; off < 8; off <<= 1) {
#pragma unroll
        for (int j = 0; j < 8; ++j) {
            s[j] += __shfl_xor(s[j], off);
            s2[j] += __shfl_xor(s2[j], off);
        }
    }
    const float* gp = gamma + (size_t)node * 64 + fg * 8;
    const float* bp = beta + (size_t)node * 64 + fg * 8;
#pragma unroll
    for (int j = 0; j < 8; ++j) {
        float mean = s[j] * 0.125f;
        float var = fmaf(-mean, mean, s2[j] * 0.125f);
        float rs = rsqrtf(var + BN_EPS);
        float o = fmaf(gp[j] * rs, h[j] - mean, bp[j]);
        h[j] = (o >= 0.f) ? o : NEG * o;
    }
    float p[12];
#pragma unroll
    for (int k = 0; k < 4; ++k) {
#pragma unroll
        for (int c = 0; c < 3; ++c) {
            float sv = 0.f;
#pragma unroll
            for (int j = 0; j < 8; ++j)
                sv = fmaf(h[j], W2[k * 192 + (fg * 8 + j) * 3 + c], sv);
            p[k * 3 + c] = sv;
        }
    }
#pragma unroll
    for (int t = 8; t < 64; t <<= 1) {
#pragma unroll
        for (int i = 0; i < 12; ++i)
            p[i] += __shfl_xor(p[i], t);
    }
    if (fg == 0) {
        size_t bn3 = ((size_t)b * N + node) * 3;
#pragma unroll
        for (int k = 0; k < 4; ++k)
#pragma unroll
            for (int c = 0; c < 3; ++c)
                y[(size_t)k * B * N * 3 + bn3 + c] = p[k * 3 + c];
    }
}

// ------------------------- 3-dim propagation (layer 2 Horner) -------------------------

__global__ __launch_bounds__(256) void qprop_kernel(const float* __restrict__ vin, const int* __restrict__ rowptr,
                                                    const int* __restrict__ csr_src, const float* __restrict__ dis,
                                                    const float* __restrict__ add, float* __restrict__ vout) {
    int b = blockIdx.x & 7;
    int n = (blockIdx.x >> 3) * blockDim.x + threadIdx.x;
    if (n >= N) return;
    float a0 = 0.f, a1 = 0.f, a2 = 0.f;
    int beg = rowptr[n], end = rowptr[n + 1];
    if (beg < 0) beg = 0;
    if (end > E) end = E;
    const float* base = vin + (size_t)b * N * 3;
    for (int i = beg; i < end; ++i) {
        unsigned s = clamp_src(csr_src[i]);
        float w = dis[s];
        const float* p = base + (size_t)s * 3;
        a0 = fmaf(w, p[0], a0);
        a1 = fmaf(w, p[1], a1);
        a2 = fmaf(w, p[2], a2);
    }
    float dn = dis[n];
    const float* ap = add + ((size_t)b * N + n) * 3;
    float* op = vout + ((size_t)b * N + n) * 3;
    op[0] = fmaf(a0, dn, ap[0]);
    op[1] = fmaf(a1, dn, ap[1]);
    op[2] = fmaf(a2, dn, ap[2]);
}

__global__ __launch_bounds__(256) void qfinal_kernel(const float* __restrict__ vin, const int* __restrict__ rowptr,
                                                     const int* __restrict__ csr_src, const float* __restrict__ dis,
                                                     const float* __restrict__ y0, const float* __restrict__ b2,
                                                     const float* __restrict__ vmin, const float* __restrict__ vmax,
                                                     float* __restrict__ out) {
    int b = blockIdx.x & 7;
    int n = (blockIdx.x >> 3) * blockDim.x + threadIdx.x;
    if (n >= N) return;
    float a0 = 0.f, a1 = 0.f, a2 = 0.f;
    int beg = rowptr[n], end = rowptr[n + 1];
    if (beg < 0) beg = 0;
    if (end > E) end = E;
    const float* base = vin + (size_t)b * N * 3;
    for (int i = beg; i < end; ++i) {
        unsigned s = clamp_src(csr_src[i]);
        float w = dis[s];
        const float* p = base + (size_t)s * 3;
        a0 = fmaf(w, p[0], a0);
        a1 = fmaf(w, p[1], a1);
        a2 = fmaf(w, p[2], a2);
    }
    float dn = dis[n];
    size_t bn3 = ((size_t)b * N + n) * 3;
    const float* yp = y0 + bn3;
    float g0 = fmaf(a0, dn, yp[0]) + b2[0];
    float g1 = fmaf(a1, dn, yp[1]) + b2[1];
    float g2 = fmaf(a2, dn, yp[2]) + b2[2];
    float mn0 = vmin[n * 3 + 0], mx0 = vmax[n * 3 + 0];
    float mn1 = vmin[n * 3 + 1], mx1 = vmax[n * 3 + 1];
    float mn2 = vmin[n * 3 + 2], mx2 = vmax[n * 3 + 2];
    float* op = out + bn3;
    op[0] = mn0 + (mx0 - mn0) / (1.f + expf(g0));
    op[1] = mn1 + (mx1 - mn1) / (1.f + expf(g1));
    op[2] = mn2 + (mx2 - mn2) / (1.f + expf(g2));
}

// ------------------------- host launcher -------------------------

extern "C" void kernel_launch(void* const* d_in, const int* in_sizes, int n_in,
                              void* d_out, int out_size, void* d_ws, size_t ws_size,
                              hipStream_t stream) {
    const float* x      = (const float*)d_in[0];
    const int*   ei     = (const int*)d_in[1];
    const int*   rowi   = ei;
    const int*   coli   = ei + E;
    const float* vmin   = (const float*)d_in[2];
    const float* vmax   = (const float*)d_in[3];
    const float* W0     = (const float*)d_in[4];
    const float* W1     = (const float*)d_in[6];
    const float* b1v    = (const float*)d_in[7];
    const float* W2     = (const float*)d_in[8];
    const float* b2v    = (const float*)d_in[9];
    const float* gamma0 = (const float*)d_in[10];
    const float* beta0  = (const float*)d_in[11];
    const float* gamma1 = (const float*)d_in[12];
    const float* beta1  = (const float*)d_in[13];
    float* out = (float*)d_out;

    const size_t BN3  = (size_t)B * N * 3;
    const size_t H1FL = (size_t)B * N * 32;        // 12.8M fl = 51.2 MB
    const size_t UCFL = (size_t)4 * N * 32;        // 6.4M fl  = 25.6 MB
    const size_t XBFL = (size_t)B * N * 2;

    auto rnd = [](size_t nf) { return (nf + 63) & ~(size_t)63; };
    size_t off = 0;
    auto alloc = [&](size_t nfloats) -> float* {
        float* p = (float*)d_ws + off;
        off += rnd(nfloats);
        return p;
    };
    // zero-block: deg, cursor, hist, bincur contiguous -> one memset
    float* deg     = alloc(N);                     // becomes dis after rank_dis
    int*   cursor  = (int*)alloc(N);
    int*   hist    = (int*)alloc(1024);
    int*   bincur  = (int*)alloc(1024);
    size_t zero_bytes = (rnd(N) * 2 + 2048) * 4;
    int*   rowptr  = (int*)alloc(N + 1);
    int*   part    = (int*)alloc(N);
    int*   bsum    = (int*)alloc(256);
    int*   boff    = (int*)alloc(256);
    int*   binstart= (int*)alloc(1024);
    int*   perm    = (int*)alloc(N);
    int*   csr_src = (int*)alloc(E);
    float* h1      = alloc(H1FL);

    const size_t avail_fl = ws_size / 4;
    const size_t need_full = off + 2 * H1FL + 4096;
    bool full = (avail_fl >= need_full);

    float *uA, *uB, *uC = nullptr;
    if (full) {
        uA = alloc(H1FL);
        uB = alloc(H1FL);
    } else {
        uA = alloc(UCFL);
        uB = alloc(UCFL);
        uC = alloc(UCFL);
    }
    uint2* xb1 = (uint2*)uA;
    uint2* xb2 = (uint2*)((float*)uA + XBFL);
    uint2* xb3 = (uint2*)((float*)uA + 2 * XBFL);
    float* y   = h1;
    float* v_a = h1 + rnd(4 * BN3);
    float* v_b = v_a + rnd(BN3);

    const int GE  = (E + 255) / 256;
    const int GN  = (N + 255) / 256;               // 196
    const int GB8 = GN * 8;
    const int GH4 = GN * 4;
    const int GW  = (N * 64) / 256;
    dim3 blk(256);

    // CSR build + degree permutation
    hipMemsetAsync(deg, 0, zero_bytes, stream);
    deg_kernel<<<GE, blk, 0, stream>>>(coli, deg);
    scan1_kernel<<<GN, blk, 0, stream>>>(deg, part, bsum);
    scan2_kernel<<<1, blk, 0, stream>>>(bsum, boff, GN, rowptr);
    scan3_kernel<<<GN, blk, 0, stream>>>(part, boff, rowptr);
    fill_kernel<<<GE, blk, 0, stream>>>(rowi, coli, rowptr, cursor, csr_src);
    hist_kernel<<<GN, blk, 0, stream>>>(deg, hist);
    hscan_kernel<<<1, blk, 0, stream>>>(hist, binstart);
    rank_dis_kernel<<<GN, blk, 0, stream>>>(deg, binstart, bincur, perm);
    const float* dis = deg;

    // layer 0
    xprop_kernel<false><<<GB8, blk, 0, stream>>>(x,   rowptr, csr_src, dis, xb1);
    xprop_kernel<true><<<GB8, blk, 0, stream>>>(xb1, rowptr, csr_src, dis, xb2);
    xprop_kernel<true><<<GB8, blk, 0, stream>>>(xb2, rowptr, csr_src, dis, xb3);
    build_h1_kernel<<<GW, blk, 0, stream>>>((const float4*)x, xb1, xb2, xb3, W0, gamma0, beta0, (uint4*)h1);

    const uint4* H1 = (const uint4*)h1;
    if (full) {
        hopM_kernel<0><<<GB8, blk, 0, stream>>>(nullptr, rowptr, csr_src, dis, perm, H1, 0, 7, 3,
                                                W1 + 3 * 4096, nullptr, (uint4*)uA);
        hopM_kernel<1><<<GB8, blk, 0, stream>>>((const uint4*)uA, rowptr, csr_src, dis, perm, H1, 0, 7, 3,
                                                W1 + 2 * 4096, nullptr, (uint4*)uB);
        hopM_kernel<1><<<GB8, blk, 0, stream>>>((const uint4*)uB, rowptr, csr_src, dis, perm, H1, 0, 7, 3,
                                                W1 + 1 * 4096, nullptr, (uint4*)uA);
        hopM_kernel<2><<<GB8, blk, 0, stream>>>((const uint4*)uA, rowptr, csr_src, dis, perm, H1, 0, 7, 3,
                                                W1, b1v, (uint4*)uB);
        bn_project_kernel<<<GW, blk, 0, stream>>>((const uint4*)uB, (const uint4*)(uB + 4 * (size_t)N * 32),
                                                  gamma1, beta1, W2, y);
    } else {
        hopM_kernel<0><<<GB8, blk, 0, stream>>>(nullptr, rowptr, csr_src, dis, perm, H1, 0, 7, 3,
                                                W1 + 3 * 4096, nullptr, (uint4*)uA);
        hopM_kernel<1><<<GH4, blk, 0, stream>>>((const uint4*)uA, rowptr, csr_src, dis, perm, H1, 0, 3, 2,
                                                W1 + 2 * 4096, nullptr, (uint4*)uC);
        hopM_kernel<1><<<GH4, blk, 0, stream>>>((const uint4*)uC, rowptr, csr_src, dis, perm, H1, 0, 3, 2,
                                                W1 + 1 * 4096, nullptr, (uint4*)uA);
        hopM_kernel<2><<<GH4, blk, 0, stream>>>((const uint4*)uA, rowptr, csr_src, dis, perm, H1, 0, 3, 2,
                                                W1, b1v, (uint4*)uC);
        hopM_kernel<1><<<GH4, blk, 0, stream>>>((const uint4*)uB, rowptr, csr_src, dis, perm, H1, 4, 3, 2,
                                                W1 + 2 * 4096, nullptr, (uint4*)uA);
        hopM_kernel<1><<<GH4, blk, 0, stream>>>((const uint4*)uA, rowptr, csr_src, dis, perm, H1, 4, 3, 2,
                                                W1 + 1 * 4096, nullptr, (uint4*)uB);
        hopM_kernel<2><<<GH4, blk, 0, stream>>>((const uint4*)uB, rowptr, csr_src, dis, perm, H1, 4, 3, 2,
                                                W1, b1v, (uint4*)uA);
        bn_project_kernel<<<GW, blk, 0, stream>>>((const uint4*)uC, (const uint4*)uA,
                                                  gamma1, beta1, W2, y);
    }

    // layer 2 Horner at 3-dim
    qprop_kernel<<<GB8, blk, 0, stream>>>(y + 3 * BN3, rowptr, csr_src, dis, y + 2 * BN3, v_a);
    qprop_kernel<<<GB8, blk, 0, stream>>>(v_a, rowptr, csr_src, dis, y + 1 * BN3, v_b);
    qfinal_kernel<<<GB8, blk, 0, stream>>>(v_b, rowptr, csr_src, dis, y, b2v, vmin, vmax, out);
}

// Round 14
// 942.319 us; speedup vs baseline: 1.8380x; 1.3616x over previous
//
#include <hip/hip_runtime.h>
#include <math.h>

constexpr int B = 8;
constexpr int N = 50000;
constexpr int E = 400000;
constexpr float BN_EPS = 1e-5f;
constexpr float NEG = 0.01f;

// ------------------------- bf16 helpers -------------------------

__device__ __forceinline__ unsigned clamp_src(int s) {
    unsigned u = (unsigned)s;
    return (u < (unsigned)N) ? u : 0u;
}

__device__ __forceinline__ unsigned pack_bf16(float a, float b) {
    unsigned ua = __float_as_uint(a);
    unsigned ub = __float_as_uint(b);
    ua = (ua + 0x7FFFu + ((ua >> 16) & 1u)) >> 16;
    ub = (ub + 0x7FFFu + ((ub >> 16) & 1u)) >> 16;
    return (ub << 16) | (ua & 0xFFFFu);
}
__device__ __forceinline__ float unpack_lo(unsigned u) { return __uint_as_float(u << 16); }
__device__ __forceinline__ float unpack_hi(unsigned u) { return __uint_as_float(u & 0xFFFF0000u); }

__device__ __forceinline__ void store_row64_bf(uint4* p, const float acc[64]) {
#pragma unroll
    for (int q = 0; q < 8; ++q) {
        uint4 v;
        v.x = pack_bf16(acc[q * 8 + 0], acc[q * 8 + 1]);
        v.y = pack_bf16(acc[q * 8 + 2], acc[q * 8 + 3]);
        v.z = pack_bf16(acc[q * 8 + 4], acc[q * 8 + 5]);
        v.w = pack_bf16(acc[q * 8 + 6], acc[q * 8 + 7]);
        p[q] = v;
    }
}

// ------------------------- CSR construction -------------------------

__global__ __launch_bounds__(256) void deg_kernel(const int* __restrict__ col, float* __restrict__ deg) {
    int e = blockIdx.x * blockDim.x + threadIdx.x;
    if (e < E) atomicAdd(&deg[clamp_src(col[e])], 1.0f);
}

__global__ __launch_bounds__(256) void scan1_kernel(const float* __restrict__ deg,
                                                    int* __restrict__ part, int* __restrict__ bsum) {
    __shared__ int sm[4];
    int i = blockIdx.x * blockDim.x + threadIdx.x;
    int v = (i < N) ? (int)deg[i] : 0;
    int lane = threadIdx.x & 63, wv = threadIdx.x >> 6;
    int x = v;
#pragma unroll
    for (int off = 1; off < 64; off <<= 1) {
        int t = __shfl_up(x, off);
        if (lane >= off) x += t;
    }
    if (lane == 63) sm[wv] = x;
    __syncthreads();
    int add = 0;
#pragma unroll
    for (int w = 0; w < 4; ++w) if (w < wv) add += sm[w];
    if (i < N) part[i] = x - v + add;
    if (threadIdx.x == blockDim.x - 1) bsum[blockIdx.x] = x + add;
}

__global__ __launch_bounds__(256) void scan2_kernel(const int* __restrict__ bsum, int* __restrict__ boff,
                                                    int nb, int* __restrict__ rowptr) {
    __shared__ int sm[4];
    int i = threadIdx.x;
    int v = (i < nb) ? bsum[i] : 0;
    int lane = i & 63, wv = i >> 6;
    int x = v;
#pragma unroll
    for (int off = 1; off < 64; off <<= 1) {
        int t = __shfl_up(x, off);
        if (lane >= off) x += t;
    }
    if (lane == 63) sm[wv] = x;
    __syncthreads();
    int add = 0;
#pragma unroll
    for (int w = 0; w < 4; ++w) if (w < wv) add += sm[w];
    if (i < nb) boff[i] = x - v + add;
    if (i == 0) rowptr[N] = E;
}

__global__ __launch_bounds__(256) void scan3_kernel(const int* __restrict__ part, const int* __restrict__ boff,
                                                    int* __restrict__ rowptr) {
    int i = blockIdx.x * blockDim.x + threadIdx.x;
    if (i < N) rowptr[i] = part[i] + boff[blockIdx.x];
}

__global__ __launch_bounds__(256) void fill_kernel(const int* __restrict__ row, const int* __restrict__ col,
                                                   const int* __restrict__ rowptr,
                                                   int* __restrict__ cursor, int* __restrict__ csr_src) {
    int e = blockIdx.x * blockDim.x + threadIdx.x;
    if (e >= E) return;
    unsigned r = clamp_src(row[e]), c = clamp_src(col[e]);
    unsigned p = (unsigned)(rowptr[c] + atomicAdd(&cursor[c], 1));
    if (p >= (unsigned)E) p = E - 1;
    csr_src[p] = (int)r;
}

// ------------- degree-uniform permutation: two-level LDS-aggregated counting sort -------

__global__ __launch_bounds__(256) void hist_kernel(const float* __restrict__ deg, int* __restrict__ hist) {
    __shared__ int lh[1024];
    for (int i = threadIdx.x; i < 1024; i += 256) lh[i] = 0;
    __syncthreads();
    int n = blockIdx.x * blockDim.x + threadIdx.x;
    if (n < N) {
        int d = (int)deg[n];
        if (d > 1023) d = 1023;
        atomicAdd(&lh[d], 1);          // LDS atomic: fast
    }
    __syncthreads();
    for (int i = threadIdx.x; i < 1024; i += 256) {
        int c = lh[i];
        if (c) atomicAdd(&hist[i], c); // one global atomic per (block, nonzero bin)
    }
}

// exclusive scan of 1024 bins (single 256-thread block, 4 bins/thread)
__global__ __launch_bounds__(256) void hscan_kernel(const int* __restrict__ hist, int* __restrict__ binstart) {
    __shared__ int sm[4];
    int t = threadIdx.x;
    int h0 = hist[t * 4 + 0], h1 = hist[t * 4 + 1], h2 = hist[t * 4 + 2], h3 = hist[t * 4 + 3];
    int sum = h0 + h1 + h2 + h3;
    int lane = t & 63, wv = t >> 6;
    int x = sum;
#pragma unroll
    for (int off = 1; off < 64; off <<= 1) {
        int v = __shfl_up(x, off);
        if (lane >= off) x += v;
    }
    if (lane == 63) sm[wv] = x;
    __syncthreads();
    int add = 0;
#pragma unroll
    for (int w = 0; w < 4; ++w) if (w < wv) add += sm[w];
    int excl = x - sum + add;
    binstart[t * 4 + 0] = excl;
    binstart[t * 4 + 1] = excl + h0;
    binstart[t * 4 + 2] = excl + h0 + h1;
    binstart[t * 4 + 3] = excl + h0 + h1 + h2;
}

// rank nodes by degree -> perm (two-level: LDS local rank + one global atomic per bin/block);
// also deg -> dis in place. Any within-bin order is a valid permutation.
__global__ __launch_bounds__(256) void rank_dis_kernel(float* __restrict__ deg, const int* __restrict__ binstart,
                                                       int* __restrict__ bincur, int* __restrict__ perm) {
    __shared__ int lh[1024];
    __shared__ int lbase[1024];
    int t = threadIdx.x;
    for (int i = t; i < 1024; i += 256) lh[i] = 0;
    __syncthreads();
    int n = blockIdx.x * blockDim.x + t;
    int di = 0, lr = 0;
    float d = 0.f;
    if (n < N) {
        d = deg[n];
        di = (int)d;
        if (di > 1023) di = 1023;
        lr = atomicAdd(&lh[di], 1);    // local rank within (block, bin)
    }
    __syncthreads();
    for (int i = t; i < 1024; i += 256) {
        int c = lh[i];
        lbase[i] = c ? atomicAdd(&bincur[i], c) : 0;
    }
    __syncthreads();
    if (n < N) {
        int r = binstart[di] + lbase[di] + lr;
        if ((unsigned)r < (unsigned)N) perm[r] = n;
        deg[n] = (d > 0.f) ? rsqrtf(d) : 0.f;
    }
}

// ------------------------- 4-dim propagation (layer 0), batch-pinned, bf16 out ---------

template<bool INBF>
__global__ __launch_bounds__(256) void xprop_kernel(const void* __restrict__ xin, const int* __restrict__ rowptr,
                                                    const int* __restrict__ csr_src, const float* __restrict__ dis,
                                                    uint2* __restrict__ xout) {
    int b = blockIdx.x & 7;
    int n = (blockIdx.x >> 3) * blockDim.x + threadIdx.x;
    if (n >= N) return;
    float a0 = 0.f, a1 = 0.f, a2 = 0.f, a3 = 0.f;
    int beg = rowptr[n], end = rowptr[n + 1];
    if (beg < 0) beg = 0;
    if (end > E) end = E;
    for (int i = beg; i < end; ++i) {
        unsigned s = clamp_src(csr_src[i]);
        float w = dis[s];
        if constexpr (!INBF) {
            float4 v = *((const float4*)xin + (size_t)b * N + s);
            a0 = fmaf(w, v.x, a0); a1 = fmaf(w, v.y, a1);
            a2 = fmaf(w, v.z, a2); a3 = fmaf(w, v.w, a3);
        } else {
            uint2 v = *((const uint2*)xin + (size_t)b * N + s);
            a0 = fmaf(w, unpack_lo(v.x), a0); a1 = fmaf(w, unpack_hi(v.x), a1);
            a2 = fmaf(w, unpack_lo(v.y), a2); a3 = fmaf(w, unpack_hi(v.y), a3);
        }
    }
    float dn = dis[n];
    uint2 o;
    o.x = pack_bf16(a0 * dn, a1 * dn);
    o.y = pack_bf16(a2 * dn, a3 * dn);
    xout[(size_t)b * N + n] = o;
}

// ------------------------- 16-dim concat row loader -------------------------

__device__ __forceinline__ void load_xv(const float4* __restrict__ x0, const uint2* __restrict__ x1,
                                        const uint2* __restrict__ x2, const uint2* __restrict__ x3,
                                        size_t ro, float xv[16]) {
    float4 v = x0[ro];
    xv[0] = v.x; xv[1] = v.y; xv[2] = v.z; xv[3] = v.w;
    uint2 u1 = x1[ro], u2 = x2[ro], u3 = x3[ro];
    xv[4] = unpack_lo(u1.x); xv[5] = unpack_hi(u1.x); xv[6] = unpack_lo(u1.y); xv[7] = unpack_hi(u1.y);
    xv[8] = unpack_lo(u2.x); xv[9] = unpack_hi(u2.x); xv[10] = unpack_lo(u2.y); xv[11] = unpack_hi(u2.y);
    xv[12] = unpack_lo(u3.x); xv[13] = unpack_hi(u3.x); xv[14] = unpack_lo(u3.y); xv[15] = unpack_hi(u3.y);
}

// ------------------------- build h1 = leaky(BN0([x|x1|x2|x3] @ W0)), bf16 full batch ----

__global__ __launch_bounds__(256) void build_h1_kernel(const float4* __restrict__ x0, const uint2* __restrict__ x1,
                                                       const uint2* __restrict__ x2, const uint2* __restrict__ x3,
                                                       const float* __restrict__ W0,
                                                       const float* __restrict__ gamma, const float* __restrict__ beta,
                                                       uint4* __restrict__ h1) {
    int gid = blockIdx.x * blockDim.x + threadIdx.x;
    int node = gid >> 6;
    int lane = gid & 63;
    int fg = lane >> 3, b = lane & 7;
    if (node >= N) return;
    size_t ro = (size_t)b * N + node;
    float xv[16];
    load_xv(x0, x1, x2, x3, ro, xv);
    float z[8];
#pragma unroll
    for (int j = 0; j < 8; ++j) z[j] = 0.f;
#pragma unroll
    for (int kf = 0; kf < 16; ++kf) {
        const float* wr = W0 + kf * 64 + fg * 8;
        float4 wa = *(const float4*)wr;
        float4 wb = *(const float4*)(wr + 4);
        float xs = xv[kf];
        z[0] = fmaf(xs, wa.x, z[0]); z[1] = fmaf(xs, wa.y, z[1]);
        z[2] = fmaf(xs, wa.z, z[2]); z[3] = fmaf(xs, wa.w, z[3]);
        z[4] = fmaf(xs, wb.x, z[4]); z[5] = fmaf(xs, wb.y, z[5]);
        z[6] = fmaf(xs, wb.z, z[6]); z[7] = fmaf(xs, wb.w, z[7]);
    }
    float s[8], s2[8];
#pragma unroll
    for (int j = 0; j < 8; ++j) { s[j] = z[j]; s2[j] = z[j] * z[j]; }
#pragma unroll
    for (int off = 1; off < 8; off <<= 1) {
#pragma unroll
        for (int j = 0; j < 8; ++j) {
            s[j] += __shfl_xor(s[j], off);
            s2[j] += __shfl_xor(s2[j], off);
        }
    }
    const float* gp = gamma + (size_t)node * 64 + fg * 8;
    const float* bp = beta + (size_t)node * 64 + fg * 8;
    float h[8];
#pragma unroll
    for (int j = 0; j < 8; ++j) {
        float mean = s[j] * 0.125f;
        float var = fmaf(-mean, mean, s2[j] * 0.125f);
        float rs = rsqrtf(var + BN_EPS);
        float o = fmaf(gp[j] * rs, z[j] - mean, bp[j]);
        h[j] = (o >= 0.f) ? o : NEG * o;
    }
    uint4 o;
    o.x = pack_bf16(h[0], h[1]);
    o.y = pack_bf16(h[2], h[3]);
    o.z = pack_bf16(h[4], h[5]);
    o.w = pack_bf16(h[6], h[7]);
    h1[ro * 8 + fg] = o;
}

// ------------------------- bf16 gather (pair-pipelined) + dense 64x64 -------------------

__device__ __forceinline__ void fma_row(float acc[64], float w, const uint4 r[8]) {
#pragma unroll
    for (int q = 0; q < 8; ++q) {
        uint4 v = r[q];
        acc[q * 8 + 0] = fmaf(w, unpack_lo(v.x), acc[q * 8 + 0]);
        acc[q * 8 + 1] = fmaf(w, unpack_hi(v.x), acc[q * 8 + 1]);
        acc[q * 8 + 2] = fmaf(w, unpack_lo(v.y), acc[q * 8 + 2]);
        acc[q * 8 + 3] = fmaf(w, unpack_hi(v.y), acc[q * 8 + 3]);
        acc[q * 8 + 4] = fmaf(w, unpack_lo(v.z), acc[q * 8 + 4]);
        acc[q * 8 + 5] = fmaf(w, unpack_hi(v.z), acc[q * 8 + 5]);
        acc[q * 8 + 6] = fmaf(w, unpack_lo(v.w), acc[q * 8 + 6]);
        acc[q * 8 + 7] = fmaf(w, unpack_hi(v.w), acc[q * 8 + 7]);
    }
}

__device__ __forceinline__ void gather64_bf(const uint4* __restrict__ ub8, int beg, int end,
                                            const int* __restrict__ csr_src, const float* __restrict__ dis,
                                            float acc[64]) {
    if (beg < 0) beg = 0;
    if (end > E) end = E;
    int i = beg;
    for (; i + 1 < end; i += 2) {
        unsigned s0 = clamp_src(csr_src[i]);
        unsigned s1 = clamp_src(csr_src[i + 1]);
        float w0 = dis[s0], w1 = dis[s1];
        const uint4* p0 = ub8 + (size_t)s0 * 8;
        const uint4* p1 = ub8 + (size_t)s1 * 8;
        uint4 r0[8], r1[8];
#pragma unroll
        for (int q = 0; q < 8; ++q) r0[q] = p0[q];
#pragma unroll
        for (int q = 0; q < 8; ++q) r1[q] = p1[q];
        fma_row(acc, w0, r0);
        fma_row(acc, w1, r1);
    }
    if (i < end) {
        unsigned s0 = clamp_src(csr_src[i]);
        float w0 = dis[s0];
        const uint4* p0 = ub8 + (size_t)s0 * 8;
        uint4 r0[8];
#pragma unroll
        for (int q = 0; q < 8; ++q) r0[q] = p0[q];
        fma_row(acc, w0, r0);
    }
}

__device__ __forceinline__ void dense64_bf(const uint4* __restrict__ hp8, const float* __restrict__ W, float acc[64]) {
#pragma unroll 1
    for (int kk = 0; kk < 4; ++kk) {
        float hreg[16];
        uint4 va = hp8[kk * 2], vb = hp8[kk * 2 + 1];
        hreg[0] = unpack_lo(va.x); hreg[1] = unpack_hi(va.x);
        hreg[2] = unpack_lo(va.y); hreg[3] = unpack_hi(va.y);
        hreg[4] = unpack_lo(va.z); hreg[5] = unpack_hi(va.z);
        hreg[6] = unpack_lo(va.w); hreg[7] = unpack_hi(va.w);
        hreg[8] = unpack_lo(vb.x); hreg[9] = unpack_hi(vb.x);
        hreg[10] = unpack_lo(vb.y); hreg[11] = unpack_hi(vb.y);
        hreg[12] = unpack_lo(vb.z); hreg[13] = unpack_hi(vb.z);
        hreg[14] = unpack_lo(vb.w); hreg[15] = unpack_hi(vb.w);
        const float* Wp = W + kk * 16 * 64;
#pragma unroll
        for (int k = 0; k < 16; ++k) {
            float hv = hreg[k];
#pragma unroll
            for (int c = 0; c < 64; ++c)
                acc[c] = fmaf(hv, Wp[k * 64 + c], acc[c]);
        }
    }
}

// ------------------------- Horner hop (thread = full row; degree-sorted for MODE>0) -----

template<int MODE>
__global__ __launch_bounds__(256) void hopM_kernel(const uint4* __restrict__ u_in, const int* __restrict__ rowptr,
                                                   const int* __restrict__ csr_src, const float* __restrict__ dis,
                                                   const int* __restrict__ perm,
                                                   const uint4* __restrict__ h1, int b0, int bmask, int bshift,
                                                   const float* __restrict__ Wk, const float* __restrict__ bias,
                                                   uint4* __restrict__ u_out) {
    int bl = blockIdx.x & bmask;
    int r = (blockIdx.x >> bshift) * blockDim.x + threadIdx.x;
    if (r >= N) return;
    int n;
    if constexpr (MODE > 0) n = (int)clamp_src(perm[r]);
    else n = r;
    float acc[64];
#pragma unroll
    for (int f = 0; f < 64; ++f) acc[f] = 0.f;
    if constexpr (MODE > 0) {
        gather64_bf(u_in + (size_t)bl * N * 8, rowptr[n], rowptr[n + 1], csr_src, dis, acc);
        float dn = dis[n];
#pragma unroll
        for (int f = 0; f < 64; ++f) acc[f] *= dn;
    }
    if constexpr (MODE == 2) {
#pragma unroll
        for (int f = 0; f < 64; ++f) acc[f] += bias[f];
    }
    dense64_bf(h1 + ((size_t)(b0 + bl) * N + n) * 8, Wk, acc);
    store_row64_bf(u_out + ((size_t)bl * N + n) * 8, acc);
}

// ------------------------- BN1 + leaky + W2 projection -------------------------

__global__ __launch_bounds__(256) void bn_project_kernel(const uint4* __restrict__ zlo, const uint4* __restrict__ zhi,
                                                         const float* __restrict__ gamma, const float* __restrict__ beta,
                                                         const float* __restrict__ W2, float* __restrict__ y) {
    int gid = blockIdx.x * blockDim.x + threadIdx.x;
    int node = gid >> 6;
    int lane = gid & 63;
    int fg = lane >> 3, b = lane & 7;
    if (node >= N) return;
    const uint4* zp = (b < 4) ? (zlo + ((size_t)b * N + node) * 8)
                              : (zhi + ((size_t)(b - 4) * N + node) * 8);
    uint4 v = zp[fg];
    float h[8] = {unpack_lo(v.x), unpack_hi(v.x), unpack_lo(v.y), unpack_hi(v.y),
                  unpack_lo(v.z), unpack_hi(v.z), unpack_lo(v.w), unpack_hi(v.w)};
    float s[8], s2[8];
#pragma unroll
    for (int j = 0; j < 8; ++j) { s[j] = h[j]; s2[j] = h[j] * h[j]; }
#pragma unroll
    for (int off = 1; off < 8; off <<= 1) {
#pragma unroll
        for (int j = 0; j < 8; ++j) {
            s[j] += __shfl_xor(s[j], off);
            s2[j] += __shfl_xor(s2[j], off);
        }
    }
    const float* gp = gamma + (size_t)node * 64 + fg * 8;
    const float* bp = beta + (size_t)node * 64 + fg * 8;
#pragma unroll
    for (int j = 0; j < 8; ++j) {
        float mean = s[j] * 0.125f;
        float var = fmaf(-mean, mean, s2[j] * 0.125f);
        float rs = rsqrtf(var + BN_EPS);
        float o = fmaf(gp[j] * rs, h[j] - mean, bp[j]);
        h[j] = (o >= 0.f) ? o : NEG * o;
    }
    float p[12];
#pragma unroll
    for (int k = 0; k < 4; ++k) {
#pragma unroll
        for (int c = 0; c < 3; ++c) {
            float sv = 0.f;
#pragma unroll
            for (int j = 0; j < 8; ++j)
                sv = fmaf(h[j], W2[k * 192 + (fg * 8 + j) * 3 + c], sv);
            p[k * 3 + c] = sv;
        }
    }
#pragma unroll
    for (int t = 8; t < 64; t <<= 1) {
#pragma unroll
        for (int i = 0; i < 12; ++i)
            p[i] += __shfl_xor(p[i], t);
    }
    if (fg == 0) {
        size_t bn3 = ((size_t)b * N + node) * 3;
#pragma unroll
        for (int k = 0; k < 4; ++k)
#pragma unroll
            for (int c = 0; c < 3; ++c)
                y[(size_t)k * B * N * 3 + bn3 + c] = p[k * 3 + c];
    }
}

// ------------------------- 3-dim propagation (layer 2 Horner) -------------------------

__global__ __launch_bounds__(256) void qprop_kernel(const float* __restrict__ vin, const int* __restrict__ rowptr,
                                                    const int* __restrict__ csr_src, const float* __restrict__ dis,
                                                    const float* __restrict__ add, float* __restrict__ vout) {
    int b = blockIdx.x & 7;
    int n = (blockIdx.x >> 3) * blockDim.x + threadIdx.x;
    if (n >= N) return;
    float a0 = 0.f, a1 = 0.f, a2 = 0.f;
    int beg = rowptr[n], end = rowptr[n + 1];
    if (beg < 0) beg = 0;
    if (end > E) end = E;
    const float* base = vin + (size_t)b * N * 3;
    for (int i = beg; i < end; ++i) {
        unsigned s = clamp_src(csr_src[i]);
        float w = dis[s];
        const float* p = base + (size_t)s * 3;
        a0 = fmaf(w, p[0], a0);
        a1 = fmaf(w, p[1], a1);
        a2 = fmaf(w, p[2], a2);
    }
    float dn = dis[n];
    const float* ap = add + ((size_t)b * N + n) * 3;
    float* op = vout + ((size_t)b * N + n) * 3;
    op[0] = fmaf(a0, dn, ap[0]);
    op[1] = fmaf(a1, dn, ap[1]);
    op[2] = fmaf(a2, dn, ap[2]);
}

__global__ __launch_bounds__(256) void qfinal_kernel(const float* __restrict__ vin, const int* __restrict__ rowptr,
                                                     const int* __restrict__ csr_src, const float* __restrict__ dis,
                                                     const float* __restrict__ y0, const float* __restrict__ b2,
                                                     const float* __restrict__ vmin, const float* __restrict__ vmax,
                                                     float* __restrict__ out) {
    int b = blockIdx.x & 7;
    int n = (blockIdx.x >> 3) * blockDim.x + threadIdx.x;
    if (n >= N) return;
    float a0 = 0.f, a1 = 0.f, a2 = 0.f;
    int beg = rowptr[n], end = rowptr[n + 1];
    if (beg < 0) beg = 0;
    if (end > E) end = E;
    const float* base = vin + (size_t)b * N * 3;
    for (int i = beg; i < end; ++i) {
        unsigned s = clamp_src(csr_src[i]);
        float w = dis[s];
        const float* p = base + (size_t)s * 3;
        a0 = fmaf(w, p[0], a0);
        a1 = fmaf(w, p[1], a1);
        a2 = fmaf(w, p[2], a2);
    }
    float dn = dis[n];
    size_t bn3 = ((size_t)b * N + n) * 3;
    const float* yp = y0 + bn3;
    float g0 = fmaf(a0, dn, yp[0]) + b2[0];
    float g1 = fmaf(a1, dn, yp[1]) + b2[1];
    float g2 = fmaf(a2, dn, yp[2]) + b2[2];
    float mn0 = vmin[n * 3 + 0], mx0 = vmax[n * 3 + 0];
    float mn1 = vmin[n * 3 + 1], mx1 = vmax[n * 3 + 1];
    float mn2 = vmin[n * 3 + 2], mx2 = vmax[n * 3 + 2];
    float* op = out + bn3;
    op[0] = mn0 + (mx0 - mn0) / (1.f + expf(g0));
    op[1] = mn1 + (mx1 - mn1) / (1.f + expf(g1));
    op[2] = mn2 + (mx2 - mn2) / (1.f + expf(g2));
}

// ------------------------- host launcher -------------------------

extern "C" void kernel_launch(void* const* d_in, const int* in_sizes, int n_in,
                              void* d_out, int out_size, void* d_ws, size_t ws_size,
                              hipStream_t stream) {
    const float* x      = (const float*)d_in[0];
    const int*   ei     = (const int*)d_in[1];
    const int*   rowi   = ei;
    const int*   coli   = ei + E;
    const float* vmin   = (const float*)d_in[2];
    const float* vmax   = (const float*)d_in[3];
    const float* W0     = (const float*)d_in[4];
    const float* W1     = (const float*)d_in[6];
    const float* b1v    = (const float*)d_in[7];
    const float* W2     = (const float*)d_in[8];
    const float* b2v    = (const float*)d_in[9];
    const float* gamma0 = (const float*)d_in[10];
    const float* beta0  = (const float*)d_in[11];
    const float* gamma1 = (const float*)d_in[12];
    const float* beta1  = (const float*)d_in[13];
    float* out = (float*)d_out;

    const size_t BN3  = (size_t)B * N * 3;
    const size_t H1FL = (size_t)B * N * 32;        // 12.8M fl = 51.2 MB
    const size_t UCFL = (size_t)4 * N * 32;        // 6.4M fl  = 25.6 MB
    const size_t XBFL = (size_t)B * N * 2;

    auto rnd = [](size_t nf) { return (nf + 63) & ~(size_t)63; };
    size_t off = 0;
    auto alloc = [&](size_t nfloats) -> float* {
        float* p = (float*)d_ws + off;
        off += rnd(nfloats);
        return p;
    };
    // zero-block: deg, cursor, hist, bincur contiguous -> one memset
    float* deg     = alloc(N);                     // becomes dis after rank_dis
    int*   cursor  = (int*)alloc(N);
    int*   hist    = (int*)alloc(1024);
    int*   bincur  = (int*)alloc(1024);
    size_t zero_bytes = (rnd(N) * 2 + 2048) * 4;
    int*   rowptr  = (int*)alloc(N + 1);
    int*   part    = (int*)alloc(N);
    int*   bsum    = (int*)alloc(256);
    int*   boff    = (int*)alloc(256);
    int*   binstart= (int*)alloc(1024);
    int*   perm    = (int*)alloc(N);
    int*   csr_src = (int*)alloc(E);
    float* h1      = alloc(H1FL);

    const size_t avail_fl = ws_size / 4;
    const size_t need_full = off + 2 * H1FL + 4096;
    bool full = (avail_fl >= need_full);

    float *uA, *uB, *uC = nullptr;
    if (full) {
        uA = alloc(H1FL);
        uB = alloc(H1FL);
    } else {
        uA = alloc(UCFL);
        uB = alloc(UCFL);
        uC = alloc(UCFL);
    }
    uint2* xb1 = (uint2*)uA;
    uint2* xb2 = (uint2*)((float*)uA + XBFL);
    uint2* xb3 = (uint2*)((float*)uA + 2 * XBFL);
    float* y   = h1;
    float* v_a = h1 + rnd(4 * BN3);
    float* v_b = v_a + rnd(BN3);

    const int GE  = (E + 255) / 256;
    const int GN  = (N + 255) / 256;               // 196
    const int GB8 = GN * 8;
    const int GH4 = GN * 4;
    const int GW  = (N * 64) / 256;
    dim3 blk(256);

    // CSR build + degree permutation (LDS-aggregated counting sort)
    hipMemsetAsync(deg, 0, zero_bytes, stream);
    deg_kernel<<<GE, blk, 0, stream>>>(coli, deg);
    scan1_kernel<<<GN, blk, 0, stream>>>(deg, part, bsum);
    scan2_kernel<<<1, blk, 0, stream>>>(bsum, boff, GN, rowptr);
    scan3_kernel<<<GN, blk, 0, stream>>>(part, boff, rowptr);
    fill_kernel<<<GE, blk, 0, stream>>>(rowi, coli, rowptr, cursor, csr_src);
    hist_kernel<<<GN, blk, 0, stream>>>(deg, hist);
    hscan_kernel<<<1, blk, 0, stream>>>(hist, binstart);
    rank_dis_kernel<<<GN, blk, 0, stream>>>(deg, binstart, bincur, perm);
    const float* dis = deg;

    // layer 0
    xprop_kernel<false><<<GB8, blk, 0, stream>>>(x,   rowptr, csr_src, dis, xb1);
    xprop_kernel<true><<<GB8, blk, 0, stream>>>(xb1, rowptr, csr_src, dis, xb2);
    xprop_kernel<true><<<GB8, blk, 0, stream>>>(xb2, rowptr, csr_src, dis, xb3);
    build_h1_kernel<<<GW, blk, 0, stream>>>((const float4*)x, xb1, xb2, xb3, W0, gamma0, beta0, (uint4*)h1);

    const uint4* H1 = (const uint4*)h1;
    if (full) {
        hopM_kernel<0><<<GB8, blk, 0, stream>>>(nullptr, rowptr, csr_src, dis, perm, H1, 0, 7, 3,
                                                W1 + 3 * 4096, nullptr, (uint4*)uA);
        hopM_kernel<1><<<GB8, blk, 0, stream>>>((const uint4*)uA, rowptr, csr_src, dis, perm, H1, 0, 7, 3,
                                                W1 + 2 * 4096, nullptr, (uint4*)uB);
        hopM_kernel<1><<<GB8, blk, 0, stream>>>((const uint4*)uB, rowptr, csr_src, dis, perm, H1, 0, 7, 3,
                                                W1 + 1 * 4096, nullptr, (uint4*)uA);
        hopM_kernel<2><<<GB8, blk, 0, stream>>>((const uint4*)uA, rowptr, csr_src, dis, perm, H1, 0, 7, 3,
                                                W1, b1v, (uint4*)uB);
        bn_project_kernel<<<GW, blk, 0, stream>>>((const uint4*)uB, (const uint4*)(uB + 4 * (size_t)N * 32),
                                                  gamma1, beta1, W2, y);
    } else {
        hopM_kernel<0><<<GB8, blk, 0, stream>>>(nullptr, rowptr, csr_src, dis, perm, H1, 0, 7, 3,
                                                W1 + 3 * 4096, nullptr, (uint4*)uA);
        hopM_kernel<1><<<GH4, blk, 0, stream>>>((const uint4*)uA, rowptr, csr_src, dis, perm, H1, 0, 3, 2,
                                                W1 + 2 * 4096, nullptr, (uint4*)uC);
        hopM_kernel<1><<<GH4, blk, 0, stream>>>((const uint4*)uC, rowptr, csr_src, dis, perm, H1, 0, 3, 2,
                                                W1 + 1 * 4096, nullptr, (uint4*)uA);
        hopM_kernel<2><<<GH4, blk, 0, stream>>>((const uint4*)uA, rowptr, csr_src, dis, perm, H1, 0, 3, 2,
                                                W1, b1v, (uint4*)uC);
        hopM_kernel<1><<<GH4, blk, 0, stream>>>((const uint4*)uB, rowptr, csr_src, dis, perm, H1, 4, 3, 2,
                                                W1 + 2 * 4096, nullptr, (uint4*)uA);
        hopM_kernel<1><<<GH4, blk, 0, stream>>>((const uint4*)uA, rowptr, csr_src, dis, perm, H1, 4, 3, 2,
                                                W1 + 1 * 4096, nullptr, (uint4*)uB);
        hopM_kernel<2><<<GH4, blk, 0, stream>>>((const uint4*)uB, rowptr, csr_src, dis, perm, H1, 4, 3, 2,
                                                W1, b1v, (uint4*)uA);
        bn_project_kernel<<<GW, blk, 0, stream>>>((const uint4*)uC, (const uint4*)uA,
                                                  gamma1, beta1, W2, y);
    }

    // layer 2 Horner at 3-dim
    qprop_kernel<<<GB8, blk, 0, stream>>>(y + 3 * BN3, rowptr, csr_src, dis, y + 2 * BN3, v_a);
    qprop_kernel<<<GB8, blk, 0, stream>>>(v_a, rowptr, csr_src, dis, y + 1 * BN3, v_b);
    qfinal_kernel<<<GB8, blk, 0, stream>>>(v_b, rowptr, csr_src, dis, y, b2v, vmin, vmax, out);
}